// Round 1
// baseline (558.918 us; speedup 1.0000x reference)
//
#include <hip/hip_runtime.h>

#define BATCH 4
#define CIN 256
#define H 96
#define W 96
#define CC 64
#define OC 32

// ---------------------------------------------------------------------------
// Kernel 1: f[b,cc,i,j] = bias[cc] + sum_{cin,ku,kv} x[b,cin,i+ku-1,j+kv-1] * w[cc,cin,ku,kv]
// Block: 256 threads = 16x16 pixel tile; each thread computes 16 cc channels.
// Grid: (36 tiles, 4 cc-groups, 4 batch)
// ---------------------------------------------------------------------------
__global__ __launch_bounds__(256) void conv3x3_kernel(
    const float* __restrict__ x, const float* __restrict__ w,
    const float* __restrict__ bias, float* __restrict__ f)
{
    const int tile = blockIdx.x;          // 0..35
    const int ccg  = blockIdx.y;          // 0..3  (16 cc each)
    const int b    = blockIdx.z;
    const int tRow = tile / 6, tCol = tile % 6;
    const int i0 = tRow * 16, j0 = tCol * 16;
    const int tid = threadIdx.x;
    const int row = tid >> 4, col = tid & 15;

    __shared__ float xs[18 * 18];         // input patch (halo 1)
    __shared__ float wl[9 * 16];          // [k][cl] weight slice for current cin

    float acc[16];
#pragma unroll
    for (int q = 0; q < 16; ++q) acc[q] = 0.f;

    for (int cin = 0; cin < CIN; ++cin) {
        __syncthreads();
        // stage 18x18 input patch (zero-padded)
        for (int t = tid; t < 324; t += 256) {
            int r = t / 18, c = t % 18;
            int gi = i0 - 1 + r, gj = j0 - 1 + c;
            float v = 0.f;
            if (gi >= 0 && gi < H && gj >= 0 && gj < W)
                v = x[((b * CIN + cin) * H + gi) * W + gj];
            xs[t] = v;
        }
        // stage weights: wl[k*16+cl] = w[ccg*16+cl][cin][k]
        if (tid < 144) {
            int k = tid >> 4, cl = tid & 15;
            wl[tid] = w[(((ccg * 16 + cl) * CIN) + cin) * 9 + k];
        }
        __syncthreads();

        float p[9];
#pragma unroll
        for (int ku = 0; ku < 3; ++ku)
#pragma unroll
            for (int kv = 0; kv < 3; ++kv)
                p[ku * 3 + kv] = xs[(row + ku) * 18 + (col + kv)];

#pragma unroll
        for (int k = 0; k < 9; ++k) {
            const float4* wv = (const float4*)&wl[k * 16];
            float4 w0 = wv[0], w1 = wv[1], w2 = wv[2], w3 = wv[3];
            float pk = p[k];
            acc[0]  += pk * w0.x; acc[1]  += pk * w0.y; acc[2]  += pk * w0.z; acc[3]  += pk * w0.w;
            acc[4]  += pk * w1.x; acc[5]  += pk * w1.y; acc[6]  += pk * w1.z; acc[7]  += pk * w1.w;
            acc[8]  += pk * w2.x; acc[9]  += pk * w2.y; acc[10] += pk * w2.z; acc[11] += pk * w2.w;
            acc[12] += pk * w3.x; acc[13] += pk * w3.y; acc[14] += pk * w3.z; acc[15] += pk * w3.w;
        }
    }

    const int i = i0 + row, j = j0 + col;
#pragma unroll
    for (int cl = 0; cl < 16; ++cl) {
        int cc = ccg * 16 + cl;
        f[((b * CC + cc) * H + i) * W + j] = acc[cl] + bias[cc];
    }
}

// ---------------------------------------------------------------------------
// Kernel 2: y[b,o,i,j] = rb[o] + sum_c f[b,c,i,j] * (sum_{u,v} f[b,c,i+u-2,j+v-2]*rw[o,c,u,v])
// Block: 256 threads = 16x16 pixel tile; each thread computes 8 oc channels.
// All weights for this oc-group (8x64x25 = 51.2 KB) preloaded to LDS once.
// Grid: (36 tiles, 4 oc-groups, 4 batch)
// ---------------------------------------------------------------------------
__global__ __launch_bounds__(256) void corrproj_kernel(
    const float* __restrict__ f, const float* __restrict__ rw,
    const float* __restrict__ rb, float* __restrict__ y)
{
    const int tile = blockIdx.x;
    const int og   = blockIdx.y;          // 0..3 (8 oc each)
    const int b    = blockIdx.z;
    const int tRow = tile / 6, tCol = tile % 6;
    const int i0 = tRow * 16, j0 = tCol * 16;
    const int tid = threadIdx.x;
    const int row = tid >> 4, col = tid & 15;

    __shared__ float fs[20 * 20];         // f patch (halo 2)
    __shared__ float wl[CC * 8 * 25];     // [c][o][k], 51.2 KB, loaded once

    // preload all weights for this oc-group
    for (int t = tid; t < CC * 8 * 25; t += 256) {
        int c = t / 200, rest = t % 200;
        int o = rest / 25, k = rest % 25;
        wl[t] = rw[((og * 8 + o) * CC + c) * 25 + k];
    }

    float acc[8];
#pragma unroll
    for (int q = 0; q < 8; ++q) acc[q] = 0.f;

    for (int c = 0; c < CC; ++c) {
        __syncthreads();
        for (int t = tid; t < 400; t += 256) {
            int r = t / 20, c2 = t % 20;
            int gi = i0 - 2 + r, gj = j0 - 2 + c2;
            float v = 0.f;
            if (gi >= 0 && gi < H && gj >= 0 && gj < W)
                v = f[((b * CC + c) * H + gi) * W + gj];
            fs[t] = v;
        }
        __syncthreads();

        float p[25];
#pragma unroll
        for (int u = 0; u < 5; ++u)
#pragma unroll
            for (int v = 0; v < 5; ++v)
                p[u * 5 + v] = fs[(row + u) * 20 + (col + v)];
        float center = p[12];

        const float* wc = &wl[c * 200];
#pragma unroll
        for (int o = 0; o < 8; ++o) {
            float s = 0.f;
#pragma unroll
            for (int k = 0; k < 25; ++k) s += p[k] * wc[o * 25 + k];
            acc[o] += center * s;
        }
    }

    const int i = i0 + row, j = j0 + col;
#pragma unroll
    for (int o = 0; o < 8; ++o) {
        int oc = og * 8 + o;
        y[((b * OC + oc) * H + i) * W + j] = acc[o] + rb[oc];
    }
}

extern "C" void kernel_launch(void* const* d_in, const int* in_sizes, int n_in,
                              void* d_out, int out_size, void* d_ws, size_t ws_size,
                              hipStream_t stream) {
    const float* x  = (const float*)d_in[0];
    const float* ew = (const float*)d_in[1];
    const float* eb = (const float*)d_in[2];
    const float* rw = (const float*)d_in[3];
    const float* rb = (const float*)d_in[4];
    float* y = (float*)d_out;
    float* f = (float*)d_ws;   // 4*64*96*96*4 = 9.44 MB intermediate

    conv3x3_kernel<<<dim3(36, 4, BATCH), 256, 0, stream>>>(x, ew, eb, f);
    corrproj_kernel<<<dim3(36, 4, BATCH), 256, 0, stream>>>(f, rw, rb, y);
}

// Round 2
// 311.361 us; speedup vs baseline: 1.7951x; 1.7951x over previous
//
#include <hip/hip_runtime.h>
#include <hip/hip_bf16.h>

#define BATCH 4
#define CIN 256
#define H 96
#define W 96
#define CC 64
#define OC 32

typedef __attribute__((ext_vector_type(8))) short bf16x8;
typedef __attribute__((ext_vector_type(4))) float f32x4;

// workspace layout (bytes)
//   xt: [4][98][98][256] bf16 = 19,668,992
//   wt: [9][4][32][16][8] bf16 = 294,912
//   f : [4][64][96][96] f32   = 9,437,184
#define XT_OFF 0
#define WT_OFF 19668992
#define F_OFF  19963904

// ---------------------------------------------------------------------------
// Prologue A: weights -> bf16 MFMA-fragment layout.
// wt[k][ccg][cb][m][e] = ew[ccg*16+m][cb*8+e][k], k=ku*3+kv.
// A-frag for (chunk cb8, shift k, wave ccg): lane(g,m) loads 16B at
//   wt + k*16384 + ccg*4096 + (cb8*4+g)*128 + m*8  -> fully coalesced.
// ---------------------------------------------------------------------------
__global__ __launch_bounds__(256) void wt_kernel(const float* __restrict__ ew,
                                                 __hip_bfloat16* __restrict__ wt)
{
    int idx = blockIdx.x * 256 + threadIdx.x;      // 147456 total
    if (idx >= 9 * 4 * 32 * 16 * 8) return;
    int e   = idx & 7;
    int m   = (idx >> 3) & 15;
    int cb  = (idx >> 7) & 31;
    int ccg = (idx >> 12) & 3;
    int k   = idx >> 14;
    int cc = ccg * 16 + m, ci = cb * 8 + e;
    wt[idx] = __float2bfloat16(ew[(cc * CIN + ci) * 9 + k]);
}

// ---------------------------------------------------------------------------
// Prologue B: x -> bf16 channel-last zero-padded layout xt[b][98][98][256]
// (row/col index = global index + 1; border rows/cols are zero).
// LDS transpose per (b, row): coalesced fp32 reads, coalesced bf16x2 writes.
// ---------------------------------------------------------------------------
__global__ __launch_bounds__(256) void xt_kernel(const float* __restrict__ x,
                                                 __hip_bfloat16* __restrict__ xt)
{
    const int r = blockIdx.x;          // 0..97 (padded row)
    const int b = blockIdx.y;
    const int tid = threadIdx.x;
    __hip_bfloat16* rowp = xt + ((size_t)(b * 98 + r)) * 98 * 256;
    const int gi = r - 1;

    if (gi < 0 || gi >= H) {           // border row: zero-fill
        unsigned int* p = (unsigned int*)rowp;
        for (int t = tid; t < 98 * 256 / 2; t += 256) p[t] = 0u;
        return;
    }

    __shared__ __hip_bfloat16 lds[96][258];   // +2 pad breaks bank conflicts

    // phase 1: coalesced fp32 reads, scalar cvt into transposed LDS
    for (int cich = 0; cich < 8; ++cich) {
        int ci = cich * 32 + (tid >> 3);
        const float* src = x + ((size_t)((b * CIN + ci) * H + gi)) * W;
        for (int coli = 0; coli < 3; ++coli) {
            int col = coli * 32 + (tid & 7) * 4;
            float4 v = *(const float4*)(src + col);
            lds[col + 0][ci] = __float2bfloat16(v.x);
            lds[col + 1][ci] = __float2bfloat16(v.y);
            lds[col + 2][ci] = __float2bfloat16(v.z);
            lds[col + 3][ci] = __float2bfloat16(v.w);
        }
    }
    __syncthreads();

    // phase 2: packed u32 writes, 512B contiguous per col
    unsigned int* dst = (unsigned int*)rowp;
    for (int it = 0; it < 48; ++it) {
        int col = it * 2 + (tid >> 7);
        int ci2 = tid & 127;
        unsigned int v = *(unsigned int*)&lds[col][ci2 * 2];
        dst[(col + 1) * 128 + ci2] = v;
    }
    // zero border cols 0 and 97
    if (tid < 128) dst[tid] = 0u;
    else           dst[97 * 128 + (tid - 128)] = 0u;
}

// ---------------------------------------------------------------------------
// Main conv: f[b,cc,i,:] via 9 shifted GEMMs on mfma_f32_16x16x32_bf16.
// Block = (b, row i), 4 waves = 4 cc-groups of 16. Wave: M=16, N=96 (6 tiles),
// K-loop = 8 ci-chunks x 9 shifts. No LDS, no syncthreads; operands from
// L2-resident xt/wt with one 16B load per lane per fragment.
// ---------------------------------------------------------------------------
__global__ __launch_bounds__(256) void conv_mfma_kernel(
    const __hip_bfloat16* __restrict__ xt, const __hip_bfloat16* __restrict__ wt,
    const float* __restrict__ eb, float* __restrict__ f)
{
    const int i = blockIdx.x;              // 0..95
    const int b = blockIdx.y;
    const int wave = threadIdx.x >> 6;     // ccg
    const int lane = threadIdx.x & 63;
    const int g = lane >> 4, m = lane & 15;

    f32x4 acc[6];
#pragma unroll
    for (int nt = 0; nt < 6; ++nt) acc[nt] = (f32x4){0.f, 0.f, 0.f, 0.f};

    // lane-invariant bases (element units)
    const __hip_bfloat16* xrow = xt + (((size_t)(b * 98 + i)) * 98) * 256 + m * 256 + g * 8;
    const __hip_bfloat16* wtl  = wt + wave * 4096 + g * 128 + m * 8;

    for (int cb8 = 0; cb8 < 8; ++cb8) {
        bf16x8 a[9];
#pragma unroll
        for (int k = 0; k < 9; ++k)
            a[k] = *(const bf16x8*)(wtl + k * 16384 + cb8 * 512);

#pragma unroll
        for (int ku = 0; ku < 3; ++ku) {
#pragma unroll
            for (int kv = 0; kv < 3; ++kv) {
                const __hip_bfloat16* xp = xrow + ku * (98 * 256) + kv * 256 + cb8 * 32;
#pragma unroll
                for (int nt = 0; nt < 6; ++nt) {
                    bf16x8 bfr = *(const bf16x8*)(xp + nt * 4096);
                    acc[nt] = __builtin_amdgcn_mfma_f32_16x16x32_bf16(
                        a[ku * 3 + kv], bfr, acc[nt], 0, 0, 0);
                }
            }
        }
    }

    // epilogue: C/D layout col=lane&15, row=(lane>>4)*4+reg
    float bias[4];
#pragma unroll
    for (int r = 0; r < 4; ++r) bias[r] = eb[wave * 16 + g * 4 + r];
#pragma unroll
    for (int nt = 0; nt < 6; ++nt)
#pragma unroll
        for (int r = 0; r < 4; ++r) {
            int cc = wave * 16 + g * 4 + r;
            f[((size_t)(b * CC + cc) * H + i) * W + nt * 16 + m] = acc[nt][r] + bias[r];
        }
}

// ---------------------------------------------------------------------------
// Kernel 2 (unchanged this round): y = rb + sum_c f_center * (5x5 corr . rw)
// ---------------------------------------------------------------------------
__global__ __launch_bounds__(256) void corrproj_kernel(
    const float* __restrict__ f, const float* __restrict__ rw,
    const float* __restrict__ rb, float* __restrict__ y)
{
    const int tile = blockIdx.x;
    const int og   = blockIdx.y;
    const int b    = blockIdx.z;
    const int tRow = tile / 6, tCol = tile % 6;
    const int i0 = tRow * 16, j0 = tCol * 16;
    const int tid = threadIdx.x;
    const int row = tid >> 4, col = tid & 15;

    __shared__ float fs[20 * 20];
    __shared__ float wl[CC * 8 * 25];

    for (int t = tid; t < CC * 8 * 25; t += 256) {
        int c = t / 200, rest = t % 200;
        int o = rest / 25, k = rest % 25;
        wl[t] = rw[((og * 8 + o) * CC + c) * 25 + k];
    }

    float acc[8];
#pragma unroll
    for (int q = 0; q < 8; ++q) acc[q] = 0.f;

    for (int c = 0; c < CC; ++c) {
        __syncthreads();
        for (int t = tid; t < 400; t += 256) {
            int r = t / 20, c2 = t % 20;
            int gi = i0 - 2 + r, gj = j0 - 2 + c2;
            float v = 0.f;
            if (gi >= 0 && gi < H && gj >= 0 && gj < W)
                v = f[((b * CC + c) * H + gi) * W + gj];
            fs[t] = v;
        }
        __syncthreads();

        float p[25];
#pragma unroll
        for (int u = 0; u < 5; ++u)
#pragma unroll
            for (int v = 0; v < 5; ++v)
                p[u * 5 + v] = fs[(row + u) * 20 + (col + v)];
        float center = p[12];

        const float* wc = &wl[c * 200];
#pragma unroll
        for (int o = 0; o < 8; ++o) {
            float s = 0.f;
#pragma unroll
            for (int k = 0; k < 25; ++k) s += p[k] * wc[o * 25 + k];
            acc[o] += center * s;
        }
    }

    const int i = i0 + row, j = j0 + col;
#pragma unroll
    for (int o = 0; o < 8; ++o) {
        int oc = og * 8 + o;
        y[((b * OC + oc) * H + i) * W + j] = acc[o] + rb[oc];
    }
}

extern "C" void kernel_launch(void* const* d_in, const int* in_sizes, int n_in,
                              void* d_out, int out_size, void* d_ws, size_t ws_size,
                              hipStream_t stream) {
    const float* x  = (const float*)d_in[0];
    const float* ew = (const float*)d_in[1];
    const float* eb = (const float*)d_in[2];
    const float* rw = (const float*)d_in[3];
    const float* rb = (const float*)d_in[4];
    float* y = (float*)d_out;

    char* ws = (char*)d_ws;
    __hip_bfloat16* xt = (__hip_bfloat16*)(ws + XT_OFF);
    __hip_bfloat16* wt = (__hip_bfloat16*)(ws + WT_OFF);
    float*          f  = (float*)(ws + F_OFF);

    wt_kernel<<<576, 256, 0, stream>>>(ew, wt);
    xt_kernel<<<dim3(98, BATCH), 256, 0, stream>>>(x, xt);
    conv_mfma_kernel<<<dim3(96, BATCH), 256, 0, stream>>>(xt, wt, eb, f);
    corrproj_kernel<<<dim3(36, 4, BATCH), 256, 0, stream>>>(f, rw, rb, y);
}

// Round 3
// 156.923 us; speedup vs baseline: 3.5617x; 1.9842x over previous
//
#include <hip/hip_runtime.h>
#include <hip/hip_bf16.h>

#define BATCH 4
#define CIN 256
#define H 96
#define W 96
#define CC 64
#define OC 32

typedef __attribute__((ext_vector_type(8))) short bf16x8;
typedef __attribute__((ext_vector_type(4))) float f32x4;
typedef __attribute__((ext_vector_type(4))) unsigned short u16x4;

// workspace layout (bytes)
//   xt : [4][98][98][256] bf16 = 19,668,992
//   wt : [9][4][32][16][8] bf16 =    294,912
//   rwt: [50][2][64][8]   bf16 =    102,400
//   ft : [4][100][100][64] bf16 =  5,120,000
#define XT_OFF  0
#define WT_OFF  19668992
#define RWT_OFF 19963904
#define FT_OFF  20066304

__device__ inline unsigned short f2bf(float v) {
    __hip_bfloat16 t = __float2bfloat16(v);
    return *reinterpret_cast<unsigned short*>(&t);
}
__device__ inline float bf2f(short b) {
    return __uint_as_float(((unsigned int)(unsigned short)b) << 16);
}

// ---------------------------------------------------------------------------
// Prologue A1: conv weights -> bf16 MFMA A-fragment layout.
// wt[k][ccg][cb][m][e] = ew[ccg*16+m][cb*8+e][k]
// ---------------------------------------------------------------------------
__global__ __launch_bounds__(256) void wt_kernel(const float* __restrict__ ew,
                                                 __hip_bfloat16* __restrict__ wt)
{
    int idx = blockIdx.x * 256 + threadIdx.x;      // 147456 total
    if (idx >= 9 * 4 * 32 * 16 * 8) return;
    int e   = idx & 7;
    int m   = (idx >> 3) & 15;
    int cb  = (idx >> 7) & 31;
    int ccg = (idx >> 12) & 3;
    int k   = idx >> 14;
    int cc = ccg * 16 + m, ci = cb * 8 + e;
    wt[idx] = __float2bfloat16(ew[(cc * CIN + ci) * 9 + k]);
}

// ---------------------------------------------------------------------------
// Prologue A2: reg weights -> bf16 MFMA A-fragment layout.
// rwt[((kc*2+mt)*64 + lane)*8 + e]; lane=(g,m): A[m][g*8+e] for chunk kc.
// global k = kc*32 + g*8 + e; uv = k>>6; c = k&63; o = mt*16+m.
// ---------------------------------------------------------------------------
__global__ __launch_bounds__(256) void rwt_kernel(const float* __restrict__ rw,
                                                  __hip_bfloat16* __restrict__ rwt)
{
    int idx = blockIdx.x * 256 + threadIdx.x;      // 51200 total
    if (idx >= 50 * 2 * 64 * 8) return;
    int e    = idx & 7;
    int lane = (idx >> 3) & 63;
    int mt   = (idx >> 9) & 1;
    int kc   = idx >> 10;
    int g = lane >> 4, m = lane & 15;
    int o  = mt * 16 + m;
    int k  = kc * 32 + g * 8 + e;
    int uv = k >> 6, c = k & 63;
    rwt[idx] = __float2bfloat16(rw[(o * CC + c) * 25 + uv]);
}

// ---------------------------------------------------------------------------
// Prologue A3: zero ft (borders matter; interior overwritten by conv).
// ---------------------------------------------------------------------------
__global__ __launch_bounds__(256) void zero_ft_kernel(float4* __restrict__ p)
{
    p[blockIdx.x * 256 + threadIdx.x] = (float4){0.f, 0.f, 0.f, 0.f};  // 320000 total
}

// ---------------------------------------------------------------------------
// Prologue B: x -> bf16 channel-last zero-padded layout xt[b][98][98][256]
// ---------------------------------------------------------------------------
__global__ __launch_bounds__(256) void xt_kernel(const float* __restrict__ x,
                                                 __hip_bfloat16* __restrict__ xt)
{
    const int r = blockIdx.x;          // 0..97 (padded row)
    const int b = blockIdx.y;
    const int tid = threadIdx.x;
    __hip_bfloat16* rowp = xt + ((size_t)(b * 98 + r)) * 98 * 256;
    const int gi = r - 1;

    if (gi < 0 || gi >= H) {
        unsigned int* p = (unsigned int*)rowp;
        for (int t = tid; t < 98 * 256 / 2; t += 256) p[t] = 0u;
        return;
    }

    __shared__ __hip_bfloat16 lds[96][258];

    for (int cich = 0; cich < 8; ++cich) {
        int ci = cich * 32 + (tid >> 3);
        const float* src = x + ((size_t)((b * CIN + ci) * H + gi)) * W;
        for (int coli = 0; coli < 3; ++coli) {
            int col = coli * 32 + (tid & 7) * 4;
            float4 v = *(const float4*)(src + col);
            lds[col + 0][ci] = __float2bfloat16(v.x);
            lds[col + 1][ci] = __float2bfloat16(v.y);
            lds[col + 2][ci] = __float2bfloat16(v.z);
            lds[col + 3][ci] = __float2bfloat16(v.w);
        }
    }
    __syncthreads();

    unsigned int* dst = (unsigned int*)rowp;
    for (int it = 0; it < 48; ++it) {
        int col = it * 2 + (tid >> 7);
        int ci2 = tid & 127;
        unsigned int v = *(unsigned int*)&lds[col][ci2 * 2];
        dst[(col + 1) * 128 + ci2] = v;
    }
    if (tid < 128) dst[tid] = 0u;
    else           dst[97 * 128 + (tid - 128)] = 0u;
}

// ---------------------------------------------------------------------------
// Conv: 9 shifted GEMMs on mfma_f32_16x16x32_bf16.
// Epilogue writes ft[b][i+2][j+2][cc] (bf16, channel-last, halo-2 padded).
// ---------------------------------------------------------------------------
__global__ __launch_bounds__(256) void conv_mfma_kernel(
    const __hip_bfloat16* __restrict__ xt, const __hip_bfloat16* __restrict__ wt,
    const float* __restrict__ eb, __hip_bfloat16* __restrict__ ft)
{
    const int i = blockIdx.x;              // 0..95
    const int b = blockIdx.y;
    const int wave = threadIdx.x >> 6;     // ccg
    const int lane = threadIdx.x & 63;
    const int g = lane >> 4, m = lane & 15;

    f32x4 acc[6];
#pragma unroll
    for (int nt = 0; nt < 6; ++nt) acc[nt] = (f32x4){0.f, 0.f, 0.f, 0.f};

    const __hip_bfloat16* xrow = xt + (((size_t)(b * 98 + i)) * 98) * 256 + m * 256 + g * 8;
    const __hip_bfloat16* wtl  = wt + wave * 4096 + g * 128 + m * 8;

    for (int cb8 = 0; cb8 < 8; ++cb8) {
        bf16x8 a[9];
#pragma unroll
        for (int k = 0; k < 9; ++k)
            a[k] = *(const bf16x8*)(wtl + k * 16384 + cb8 * 512);

#pragma unroll
        for (int ku = 0; ku < 3; ++ku) {
#pragma unroll
            for (int kv = 0; kv < 3; ++kv) {
                const __hip_bfloat16* xp = xrow + ku * (98 * 256) + kv * 256 + cb8 * 32;
#pragma unroll
                for (int nt = 0; nt < 6; ++nt) {
                    bf16x8 bfr = *(const bf16x8*)(xp + nt * 4096);
                    acc[nt] = __builtin_amdgcn_mfma_f32_16x16x32_bf16(
                        a[ku * 3 + kv], bfr, acc[nt], 0, 0, 0);
                }
            }
        }
    }

    // epilogue: C/D layout col(n)=m, row=g*4+r; cc = wave*16+g*4+r, j = nt*16+m
    float bias[4];
#pragma unroll
    for (int r = 0; r < 4; ++r) bias[r] = eb[wave * 16 + g * 4 + r];

    __hip_bfloat16* out = ft + ((size_t)((b * 100 + i + 2) * 100 + 2)) * 64;
#pragma unroll
    for (int nt = 0; nt < 6; ++nt) {
        u16x4 pk;
#pragma unroll
        for (int r = 0; r < 4; ++r) pk[r] = f2bf(acc[nt][r] + bias[r]);
        *(u16x4*)(out + (nt * 16 + m) * 64 + wave * 16 + g * 4) = pk;
    }
}

// ---------------------------------------------------------------------------
// CorrProj as K=1600 GEMM: y[o,pix] = rb[o] + sum_k rwt[o,k] * h[k,pix],
// h[k=(uv,c)][pix] = ft_center[c,pix] * ft_shift[uv][c,pix], built in regs.
// Wave = 16-pixel row segment; uv = kc>>1 wave-uniform, c0 = (kc&1)*32+g*8.
// No LDS. Grid 576 blocks x 4 waves = 2304 tiles.
// ---------------------------------------------------------------------------
__global__ __launch_bounds__(256) void corrproj_mfma_kernel(
    const __hip_bfloat16* __restrict__ ft, const __hip_bfloat16* __restrict__ rwt,
    const float* __restrict__ rb, float* __restrict__ y)
{
    const int wave = threadIdx.x >> 6;
    const int lane = threadIdx.x & 63;
    const int g = lane >> 4, m = lane & 15;
    const int T = blockIdx.x * 4 + wave;     // 0..2303
    const int b = T / 576;
    const int rem = T % 576;
    const int i = rem / 6;
    const int j0 = (rem % 6) * 16;

    // shifted-base for this lane's pixel (row i+u has ft-row index i+u, col j0+m+v)
    const __hip_bfloat16* sbase = ft + ((size_t)((b * 100 + i) * 100 + (j0 + m))) * 64;
    const __hip_bfloat16* cbase = sbase + 202 * 64;   // center at (+2,+2)

    // per-lane center cache: c = g*8..g*8+7 (h=0) and 32+g*8..+7 (h=1), as f32
    float cen[16];
    {
        bf16x8 c0 = *(const bf16x8*)(cbase + g * 8);
        bf16x8 c1 = *(const bf16x8*)(cbase + 32 + g * 8);
#pragma unroll
        for (int e = 0; e < 8; ++e) {
            cen[e]     = bf2f(c0[e]);
            cen[8 + e] = bf2f(c1[e]);
        }
    }

    f32x4 acc0 = (f32x4){0.f, 0.f, 0.f, 0.f};
    f32x4 acc1 = (f32x4){0.f, 0.f, 0.f, 0.f};
    const __hip_bfloat16* rwl = rwt + lane * 8;

#pragma unroll
    for (int u = 0; u < 5; ++u) {
#pragma unroll
        for (int v = 0; v < 5; ++v) {
#pragma unroll
            for (int h = 0; h < 2; ++h) {
                const int kc = (u * 5 + v) * 2 + h;
                bf16x8 a0 = *(const bf16x8*)(rwl + kc * 1024);
                bf16x8 a1 = *(const bf16x8*)(rwl + kc * 1024 + 512);
                bf16x8 s  = *(const bf16x8*)(sbase + (u * 100 + v) * 64 + h * 32 + g * 8);
                bf16x8 hb;
#pragma unroll
                for (int e = 0; e < 8; ++e)
                    hb[e] = (short)f2bf(bf2f(s[e]) * cen[h * 8 + e]);
                acc0 = __builtin_amdgcn_mfma_f32_16x16x32_bf16(a0, hb, acc0, 0, 0, 0);
                acc1 = __builtin_amdgcn_mfma_f32_16x16x32_bf16(a1, hb, acc1, 0, 0, 0);
            }
        }
    }

    // epilogue: D[o][pix]: o = mt*16 + g*4 + r, pix col = m
#pragma unroll
    for (int r = 0; r < 4; ++r) {
        int o0 = g * 4 + r;
        y[((size_t)(b * OC + o0) * H + i) * W + j0 + m] = acc0[r] + rb[o0];
        int o1 = 16 + g * 4 + r;
        y[((size_t)(b * OC + o1) * H + i) * W + j0 + m] = acc1[r] + rb[o1];
    }
}

extern "C" void kernel_launch(void* const* d_in, const int* in_sizes, int n_in,
                              void* d_out, int out_size, void* d_ws, size_t ws_size,
                              hipStream_t stream) {
    const float* x  = (const float*)d_in[0];
    const float* ew = (const float*)d_in[1];
    const float* eb = (const float*)d_in[2];
    const float* rw = (const float*)d_in[3];
    const float* rb = (const float*)d_in[4];
    float* y = (float*)d_out;

    char* ws = (char*)d_ws;
    __hip_bfloat16* xt  = (__hip_bfloat16*)(ws + XT_OFF);
    __hip_bfloat16* wt  = (__hip_bfloat16*)(ws + WT_OFF);
    __hip_bfloat16* rwt = (__hip_bfloat16*)(ws + RWT_OFF);
    __hip_bfloat16* ft  = (__hip_bfloat16*)(ws + FT_OFF);

    wt_kernel<<<576, 256, 0, stream>>>(ew, wt);
    rwt_kernel<<<200, 256, 0, stream>>>(rw, rwt);
    zero_ft_kernel<<<1250, 256, 0, stream>>>((float4*)ft);
    xt_kernel<<<dim3(98, BATCH), 256, 0, stream>>>(x, xt);
    conv_mfma_kernel<<<dim3(96, BATCH), 256, 0, stream>>>(xt, wt, eb, ft);
    corrproj_mfma_kernel<<<576, 256, 0, stream>>>(ft, rwt, rb, y);
}

// Round 4
// 84.745 us; speedup vs baseline: 6.5953x; 1.8517x over previous
//
#include <hip/hip_runtime.h>
#include <hip/hip_bf16.h>

#define BATCH 4
#define CIN 256
#define H 96
#define W 96
#define CC 64
#define OC 32

typedef __attribute__((ext_vector_type(8))) short bf16x8;
typedef __attribute__((ext_vector_type(4))) float f32x4;
typedef __attribute__((ext_vector_type(4))) unsigned short u16x4;
typedef __attribute__((ext_vector_type(4))) unsigned int u32x4;

// workspace layout (bytes)
//   xt : [4][98][98][256] bf16 = 19,668,992
//   wt : [9][4][32][16][8] bf16 =    294,912
//   rwt: [50][2][64][8]   bf16 =    102,400
//   ft : [4][100][100][64] bf16 =  5,120,000
#define XT_OFF  0
#define WT_OFF  19668992
#define RWT_OFF 19963904
#define FT_OFF  20066304

__device__ inline unsigned short f2bf(float v) {
    __hip_bfloat16 t = __float2bfloat16(v);
    return *reinterpret_cast<unsigned short*>(&t);
}
__device__ inline float bf2f(short b) {
    return __uint_as_float(((unsigned int)(unsigned short)b) << 16);
}

// ---------------------------------------------------------------------------
// Prologue A1: conv weights -> bf16 MFMA A-fragment layout.
// wt[k][ccg][cb][m][e] = ew[ccg*16+m][cb*8+e][k]
// ---------------------------------------------------------------------------
__global__ __launch_bounds__(256) void wt_kernel(const float* __restrict__ ew,
                                                 __hip_bfloat16* __restrict__ wt)
{
    int idx = blockIdx.x * 256 + threadIdx.x;      // 147456 total
    if (idx >= 9 * 4 * 32 * 16 * 8) return;
    int e   = idx & 7;
    int m   = (idx >> 3) & 15;
    int cb  = (idx >> 7) & 31;
    int ccg = (idx >> 12) & 3;
    int k   = idx >> 14;
    int cc = ccg * 16 + m, ci = cb * 8 + e;
    wt[idx] = __float2bfloat16(ew[(cc * CIN + ci) * 9 + k]);
}

// ---------------------------------------------------------------------------
// Prologue A2: reg weights -> bf16 MFMA A-fragment layout.
// ---------------------------------------------------------------------------
__global__ __launch_bounds__(256) void rwt_kernel(const float* __restrict__ rw,
                                                  __hip_bfloat16* __restrict__ rwt)
{
    int idx = blockIdx.x * 256 + threadIdx.x;      // 51200 total
    if (idx >= 50 * 2 * 64 * 8) return;
    int e    = idx & 7;
    int lane = (idx >> 3) & 63;
    int mt   = (idx >> 9) & 1;
    int kc   = idx >> 10;
    int g = lane >> 4, m = lane & 15;
    int o  = mt * 16 + m;
    int k  = kc * 32 + g * 8 + e;
    int uv = k >> 6, c = k & 63;
    rwt[idx] = __float2bfloat16(rw[(o * CC + c) * 25 + uv]);
}

// ---------------------------------------------------------------------------
// Prologue A3: zero ft (borders matter; interior overwritten by conv).
// ---------------------------------------------------------------------------
__global__ __launch_bounds__(256) void zero_ft_kernel(float4* __restrict__ p)
{
    p[blockIdx.x * 256 + threadIdx.x] = (float4){0.f, 0.f, 0.f, 0.f};  // 320000 total
}

// ---------------------------------------------------------------------------
// Prologue B: x -> bf16 channel-last zero-padded layout xt[b][98][98][256]
// ---------------------------------------------------------------------------
__global__ __launch_bounds__(256) void xt_kernel(const float* __restrict__ x,
                                                 __hip_bfloat16* __restrict__ xt)
{
    const int r = blockIdx.x;          // 0..97 (padded row)
    const int b = blockIdx.y;
    const int tid = threadIdx.x;
    __hip_bfloat16* rowp = xt + ((size_t)(b * 98 + r)) * 98 * 256;
    const int gi = r - 1;

    if (gi < 0 || gi >= H) {
        unsigned int* p = (unsigned int*)rowp;
        for (int t = tid; t < 98 * 256 / 2; t += 256) p[t] = 0u;
        return;
    }

    __shared__ __hip_bfloat16 lds[96][258];

    for (int cich = 0; cich < 8; ++cich) {
        int ci = cich * 32 + (tid >> 3);
        const float* src = x + ((size_t)((b * CIN + ci) * H + gi)) * W;
        for (int coli = 0; coli < 3; ++coli) {
            int col = coli * 32 + (tid & 7) * 4;
            float4 v = *(const float4*)(src + col);
            lds[col + 0][ci] = __float2bfloat16(v.x);
            lds[col + 1][ci] = __float2bfloat16(v.y);
            lds[col + 2][ci] = __float2bfloat16(v.z);
            lds[col + 3][ci] = __float2bfloat16(v.w);
        }
    }
    __syncthreads();

    unsigned int* dst = (unsigned int*)rowp;
    for (int it = 0; it < 48; ++it) {
        int col = it * 2 + (tid >> 7);
        int ci2 = tid & 127;
        unsigned int v = *(unsigned int*)&lds[col][ci2 * 2];
        dst[(col + 1) * 128 + ci2] = v;
    }
    if (tid < 128) dst[tid] = 0u;
    else           dst[97 * 128 + (tid - 128)] = 0u;
}

// ---------------------------------------------------------------------------
// Conv v2: LDS-staged, double-buffered, 9 shifted GEMMs on mfma 16x16x32 bf16.
// Block = 128 thr (2 waves) computes 64cc x 32px of row (b,i). Grid (3,96,4).
// LDS tile per ci-chunk: [3 ku][36 px][16 dw] bf16, XOR-swizzled quads
// (quad ^= (px>>1)&3) -> 2-way max bank aliasing on ds_read_b128 (free).
// Wave w: cc = w*32..w*32+31 (2 mt), px = j0..j0+31 (2 nt).
// Per chunk per wave: 18 A-loads (wt, L1-hot) + 18 ds_read + 36 MFMA.
// Single barrier per chunk: [issue glb loads t+1][compute t][ds_write t+1][bar]
// ---------------------------------------------------------------------------
__global__ __launch_bounds__(128) void conv_mfma2_kernel(
    const __hip_bfloat16* __restrict__ xt, const __hip_bfloat16* __restrict__ wt,
    const float* __restrict__ eb, __hip_bfloat16* __restrict__ ft)
{
    const int jb = blockIdx.x;             // 0..2
    const int i  = blockIdx.y;             // 0..95
    const int b  = blockIdx.z;
    const int j0 = jb * 32;
    const int tid  = threadIdx.x;
    const int wave = tid >> 6;             // 0..1 -> cc half
    const int lane = tid & 63;
    const int g = lane >> 4, m = lane & 15;

    __shared__ __align__(16) unsigned int bbuf[2][1728];   // 2 x 6912 B

    // --- staging slot precompute: 432 units of 16B; unit u: r=u>>2, q=u&3;
    // row r: ku=r/36, p=r%36; global = xt[(b*98+i+ku)*98 + j0+p]*256 + q*8;
    // lds dword = r*16 + (q ^ ((p>>1)&3))*4.  Slots u = tid, +128, +256, +384.
    const int qq = tid & 3;
    const __hip_bfloat16 *gp0, *gp1, *gp2, *gp3;
    int lb0, lb1, lb2, lb3;
    {
        int r, ku, p;
        r = (tid >> 2);       ku = r / 36; p = r - ku * 36;
        gp0 = xt + ((size_t)((b * 98 + i + ku) * 98 + j0 + p)) * 256 + qq * 8;
        lb0 = (r * 16 + ((qq ^ ((p >> 1) & 3)) << 2)) * 4;
        r = (tid >> 2) + 32;  ku = r / 36; p = r - ku * 36;
        gp1 = xt + ((size_t)((b * 98 + i + ku) * 98 + j0 + p)) * 256 + qq * 8;
        lb1 = (r * 16 + ((qq ^ ((p >> 1) & 3)) << 2)) * 4;
        r = (tid >> 2) + 64;  ku = r / 36; p = r - ku * 36;
        gp2 = xt + ((size_t)((b * 98 + i + ku) * 98 + j0 + p)) * 256 + qq * 8;
        lb2 = (r * 16 + ((qq ^ ((p >> 1) & 3)) << 2)) * 4;
        r = (tid >> 2) + 96;  if (r > 107) r = 107;   // slot3 valid iff tid<48
        ku = r / 36; p = r - ku * 36;
        gp3 = xt + ((size_t)((b * 98 + i + ku) * 98 + j0 + p)) * 256 + qq * 8;
        lb3 = (r * 16 + ((qq ^ ((p >> 1) & 3)) << 2)) * 4;
    }
    const bool v3 = (tid < 48);

    // prologue: stage chunk 0 into buf 0
    {
        u32x4 s0 = *(const u32x4*)gp0;
        u32x4 s1 = *(const u32x4*)gp1;
        u32x4 s2 = *(const u32x4*)gp2;
        u32x4 s3 = *(const u32x4*)gp3;
        char* wb = (char*)&bbuf[0][0];
        *(u32x4*)(wb + lb0) = s0;
        *(u32x4*)(wb + lb1) = s1;
        *(u32x4*)(wb + lb2) = s2;
        if (v3) *(u32x4*)(wb + lb3) = s3;
    }
    __syncthreads();

    f32x4 acc00 = (f32x4){0.f,0.f,0.f,0.f}, acc01 = (f32x4){0.f,0.f,0.f,0.f};
    f32x4 acc10 = (f32x4){0.f,0.f,0.f,0.f}, acc11 = (f32x4){0.f,0.f,0.f,0.f};

    const __hip_bfloat16* wA0 = wt + (wave * 2 + 0) * 4096 + g * 128 + m * 8;
    const __hip_bfloat16* wA1 = wt + (wave * 2 + 1) * 4096 + g * 128 + m * 8;

    for (int t = 0; t < 8; ++t) {
        // issue next chunk's global loads early (latency hides under MFMAs)
        u32x4 s0, s1, s2, s3;
        const bool pf = (t < 7);
        if (pf) {
            const int co = (t + 1) * 32;
            s0 = *(const u32x4*)(gp0 + co);
            s1 = *(const u32x4*)(gp1 + co);
            s2 = *(const u32x4*)(gp2 + co);
            s3 = *(const u32x4*)(gp3 + co);
        }

        const unsigned int* bb = &bbuf[t & 1][0];
        const __hip_bfloat16* wa0 = wA0 + t * 512;
        const __hip_bfloat16* wa1 = wA1 + t * 512;
#pragma unroll
        for (int ku = 0; ku < 3; ++ku) {
#pragma unroll
            for (int kv = 0; kv < 3; ++kv) {
                const int k = ku * 3 + kv;
                bf16x8 a0 = *(const bf16x8*)(wa0 + k * 16384);
                bf16x8 a1 = *(const bf16x8*)(wa1 + k * 16384);
                const int px0 = m + kv, px1 = px0 + 16;
                bf16x8 b0 = *(const bf16x8*)(bb + (ku * 36 + px0) * 16 + ((g ^ ((px0 >> 1) & 3)) << 2));
                bf16x8 b1 = *(const bf16x8*)(bb + (ku * 36 + px1) * 16 + ((g ^ ((px1 >> 1) & 3)) << 2));
                acc00 = __builtin_amdgcn_mfma_f32_16x16x32_bf16(a0, b0, acc00, 0, 0, 0);
                acc01 = __builtin_amdgcn_mfma_f32_16x16x32_bf16(a0, b1, acc01, 0, 0, 0);
                acc10 = __builtin_amdgcn_mfma_f32_16x16x32_bf16(a1, b0, acc10, 0, 0, 0);
                acc11 = __builtin_amdgcn_mfma_f32_16x16x32_bf16(a1, b1, acc11, 0, 0, 0);
            }
        }

        if (pf) {
            char* wb = (char*)&bbuf[(t + 1) & 1][0];
            *(u32x4*)(wb + lb0) = s0;
            *(u32x4*)(wb + lb1) = s1;
            *(u32x4*)(wb + lb2) = s2;
            if (v3) *(u32x4*)(wb + lb3) = s3;
        }
        __syncthreads();
    }

    // epilogue -> ft[b][i+2][j0+2+px][cc] (bf16 channel-last, halo-2 padded)
    __hip_bfloat16* out = ft + ((size_t)((b * 100 + i + 2) * 100 + (j0 + 2))) * 64;
#pragma unroll
    for (int mt = 0; mt < 2; ++mt) {
        const int ccb = (wave * 2 + mt) * 16 + g * 4;
        float bias[4];
#pragma unroll
        for (int r = 0; r < 4; ++r) bias[r] = eb[ccb + r];
        f32x4 aN0 = (mt == 0) ? acc00 : acc10;
        f32x4 aN1 = (mt == 0) ? acc01 : acc11;
        u16x4 p0, p1;
#pragma unroll
        for (int r = 0; r < 4; ++r) {
            p0[r] = f2bf(aN0[r] + bias[r]);
            p1[r] = f2bf(aN1[r] + bias[r]);
        }
        *(u16x4*)(out + (0 * 16 + m) * 64 + ccb) = p0;
        *(u16x4*)(out + (1 * 16 + m) * 64 + ccb) = p1;
    }
}

// ---------------------------------------------------------------------------
// CorrProj as K=1600 GEMM (unchanged this round).
// ---------------------------------------------------------------------------
__global__ __launch_bounds__(256) void corrproj_mfma_kernel(
    const __hip_bfloat16* __restrict__ ft, const __hip_bfloat16* __restrict__ rwt,
    const float* __restrict__ rb, float* __restrict__ y)
{
    const int wave = threadIdx.x >> 6;
    const int lane = threadIdx.x & 63;
    const int g = lane >> 4, m = lane & 15;
    const int T = blockIdx.x * 4 + wave;     // 0..2303
    const int b = T / 576;
    const int rem = T % 576;
    const int i = rem / 6;
    const int j0 = (rem % 6) * 16;

    const __hip_bfloat16* sbase = ft + ((size_t)((b * 100 + i) * 100 + (j0 + m))) * 64;
    const __hip_bfloat16* cbase = sbase + 202 * 64;   // center at (+2,+2)

    float cen[16];
    {
        bf16x8 c0 = *(const bf16x8*)(cbase + g * 8);
        bf16x8 c1 = *(const bf16x8*)(cbase + 32 + g * 8);
#pragma unroll
        for (int e = 0; e < 8; ++e) {
            cen[e]     = bf2f(c0[e]);
            cen[8 + e] = bf2f(c1[e]);
        }
    }

    f32x4 acc0 = (f32x4){0.f, 0.f, 0.f, 0.f};
    f32x4 acc1 = (f32x4){0.f, 0.f, 0.f, 0.f};
    const __hip_bfloat16* rwl = rwt + lane * 8;

#pragma unroll
    for (int u = 0; u < 5; ++u) {
#pragma unroll
        for (int v = 0; v < 5; ++v) {
#pragma unroll
            for (int h = 0; h < 2; ++h) {
                const int kc = (u * 5 + v) * 2 + h;
                bf16x8 a0 = *(const bf16x8*)(rwl + kc * 1024);
                bf16x8 a1 = *(const bf16x8*)(rwl + kc * 1024 + 512);
                bf16x8 s  = *(const bf16x8*)(sbase + (u * 100 + v) * 64 + h * 32 + g * 8);
                bf16x8 hb;
#pragma unroll
                for (int e = 0; e < 8; ++e)
                    hb[e] = (short)f2bf(bf2f(s[e]) * cen[h * 8 + e]);
                acc0 = __builtin_amdgcn_mfma_f32_16x16x32_bf16(a0, hb, acc0, 0, 0, 0);
                acc1 = __builtin_amdgcn_mfma_f32_16x16x32_bf16(a1, hb, acc1, 0, 0, 0);
            }
        }
    }

#pragma unroll
    for (int r = 0; r < 4; ++r) {
        int o0 = g * 4 + r;
        y[((size_t)(b * OC + o0) * H + i) * W + j0 + m] = acc0[r] + rb[o0];
        int o1 = 16 + g * 4 + r;
        y[((size_t)(b * OC + o1) * H + i) * W + j0 + m] = acc1[r] + rb[o1];
    }
}

extern "C" void kernel_launch(void* const* d_in, const int* in_sizes, int n_in,
                              void* d_out, int out_size, void* d_ws, size_t ws_size,
                              hipStream_t stream) {
    const float* x  = (const float*)d_in[0];
    const float* ew = (const float*)d_in[1];
    const float* eb = (const float*)d_in[2];
    const float* rw = (const float*)d_in[3];
    const float* rb = (const float*)d_in[4];
    float* y = (float*)d_out;

    char* ws = (char*)d_ws;
    __hip_bfloat16* xt  = (__hip_bfloat16*)(ws + XT_OFF);
    __hip_bfloat16* wt  = (__hip_bfloat16*)(ws + WT_OFF);
    __hip_bfloat16* rwt = (__hip_bfloat16*)(ws + RWT_OFF);
    __hip_bfloat16* ft  = (__hip_bfloat16*)(ws + FT_OFF);

    wt_kernel<<<576, 256, 0, stream>>>(ew, wt);
    rwt_kernel<<<200, 256, 0, stream>>>(rw, rwt);
    zero_ft_kernel<<<1250, 256, 0, stream>>>((float4*)ft);
    xt_kernel<<<dim3(98, BATCH), 256, 0, stream>>>(x, xt);
    conv_mfma2_kernel<<<dim3(3, 96, BATCH), 128, 0, stream>>>(xt, wt, eb, ft);
    corrproj_mfma_kernel<<<576, 256, 0, stream>>>(ft, rwt, rb, y);
}

// Round 5
// 67.146 us; speedup vs baseline: 8.3239x; 1.2621x over previous
//
#include <hip/hip_runtime.h>
#include <hip/hip_bf16.h>

#define BATCH 4
#define CIN 256
#define H 96
#define W 96
#define CC 64
#define OC 32

typedef __attribute__((ext_vector_type(8))) short bf16x8;
typedef __attribute__((ext_vector_type(4))) float f32x4;
typedef __attribute__((ext_vector_type(4))) unsigned short u16x4;
typedef __attribute__((ext_vector_type(4))) unsigned int u32x4;

// workspace layout (bytes)
//   xt : [4][98][98][256] bf16 = 19,668,992
//   wt : [9][4][32][16][8] bf16 =    294,912
//   rwt: [50][2][64][8]   bf16 =    102,400
//   ft : [4][100][100][64] bf16 =  5,120,000
#define XT_OFF  0
#define WT_OFF  19668992
#define RWT_OFF 19963904
#define FT_OFF  20066304

__device__ inline unsigned short f2bf(float v) {
    __hip_bfloat16 t = __float2bfloat16(v);
    return *reinterpret_cast<unsigned short*>(&t);
}
__device__ inline float bf2f(short b) {
    return __uint_as_float(((unsigned int)(unsigned short)b) << 16);
}

// ---------------------------------------------------------------------------
// Prologue A1: conv weights -> bf16 MFMA A-fragment layout.
// wt[k][ccg][cb][m][e] = ew[ccg*16+m][cb*8+e][k]
// ---------------------------------------------------------------------------
__global__ __launch_bounds__(256) void wt_kernel(const float* __restrict__ ew,
                                                 __hip_bfloat16* __restrict__ wt)
{
    int idx = blockIdx.x * 256 + threadIdx.x;      // 147456 total
    if (idx >= 9 * 4 * 32 * 16 * 8) return;
    int e   = idx & 7;
    int m   = (idx >> 3) & 15;
    int cb  = (idx >> 7) & 31;
    int ccg = (idx >> 12) & 3;
    int k   = idx >> 14;
    int cc = ccg * 16 + m, ci = cb * 8 + e;
    wt[idx] = __float2bfloat16(ew[(cc * CIN + ci) * 9 + k]);
}

// ---------------------------------------------------------------------------
// Prologue A2: reg weights -> bf16 MFMA A-fragment layout.
// rwt[((kc*2+mt)*64 + lane)*8 + e]; k = kc*32 + g*8 + e; uv=k>>6; c=k&63.
// ---------------------------------------------------------------------------
__global__ __launch_bounds__(256) void rwt_kernel(const float* __restrict__ rw,
                                                  __hip_bfloat16* __restrict__ rwt)
{
    int idx = blockIdx.x * 256 + threadIdx.x;      // 51200 total
    if (idx >= 50 * 2 * 64 * 8) return;
    int e    = idx & 7;
    int lane = (idx >> 3) & 63;
    int mt   = (idx >> 9) & 1;
    int kc   = idx >> 10;
    int g = lane >> 4, m = lane & 15;
    int o  = mt * 16 + m;
    int k  = kc * 32 + g * 8 + e;
    int uv = k >> 6, c = k & 63;
    rwt[idx] = __float2bfloat16(rw[(o * CC + c) * 25 + uv]);
}

// ---------------------------------------------------------------------------
// Prologue A3: zero ONLY the ft border (interior is overwritten by conv).
// Border pixels: rows {0,1,98,99} x 100 + rows 2..97 x cols {0,1,98,99}
// = 784 px/batch x 128 B = 8 x16B units. 4*6272 = 25088 units, 98 blocks.
// ---------------------------------------------------------------------------
__global__ __launch_bounds__(256) void zero_ft_border_kernel(__hip_bfloat16* __restrict__ ft)
{
    int idx = blockIdx.x * 256 + threadIdx.x;
    if (idx >= 4 * 6272) return;
    int b = idx / 6272, t = idx % 6272;
    int q = t & 7, pid = t >> 3;
    int r, c;
    if (pid < 400) {
        int rr = pid / 100;
        r = (rr < 2) ? rr : rr + 96;        // {0,1,98,99}
        c = pid % 100;
    } else {
        int p2 = pid - 400;                  // 0..383
        r = 2 + (p2 >> 2);                   // 2..97
        int c2 = p2 & 3;
        c = (c2 < 2) ? c2 : c2 + 96;         // {0,1,98,99}
    }
    *(u32x4*)(ft + ((size_t)((b * 100 + r) * 100 + c)) * 64 + q * 8) = (u32x4){0u,0u,0u,0u};
}

// ---------------------------------------------------------------------------
// Prologue B: x -> bf16 channel-last zero-padded layout xt[b][98][98][256]
// ---------------------------------------------------------------------------
__global__ __launch_bounds__(256) void xt_kernel(const float* __restrict__ x,
                                                 __hip_bfloat16* __restrict__ xt)
{
    const int r = blockIdx.x;          // 0..97 (padded row)
    const int b = blockIdx.y;
    const int tid = threadIdx.x;
    __hip_bfloat16* rowp = xt + ((size_t)(b * 98 + r)) * 98 * 256;
    const int gi = r - 1;

    if (gi < 0 || gi >= H) {
        unsigned int* p = (unsigned int*)rowp;
        for (int t = tid; t < 98 * 256 / 2; t += 256) p[t] = 0u;
        return;
    }

    __shared__ __hip_bfloat16 lds[96][258];

    for (int cich = 0; cich < 8; ++cich) {
        int ci = cich * 32 + (tid >> 3);
        const float* src = x + ((size_t)((b * CIN + ci) * H + gi)) * W;
        for (int coli = 0; coli < 3; ++coli) {
            int col = coli * 32 + (tid & 7) * 4;
            float4 v = *(const float4*)(src + col);
            lds[col + 0][ci] = __float2bfloat16(v.x);
            lds[col + 1][ci] = __float2bfloat16(v.y);
            lds[col + 2][ci] = __float2bfloat16(v.z);
            lds[col + 3][ci] = __float2bfloat16(v.w);
        }
    }
    __syncthreads();

    unsigned int* dst = (unsigned int*)rowp;
    for (int it = 0; it < 48; ++it) {
        int col = it * 2 + (tid >> 7);
        int ci2 = tid & 127;
        unsigned int v = *(unsigned int*)&lds[col][ci2 * 2];
        dst[(col + 1) * 128 + ci2] = v;
    }
    if (tid < 128) dst[tid] = 0u;
    else           dst[97 * 128 + (tid - 128)] = 0u;
}

// ---------------------------------------------------------------------------
// Conv: LDS-staged, double-buffered, 9 shifted GEMMs on mfma 16x16x32 bf16.
// Block = 128 thr (2 waves) computes 64cc x 32px of row (b,i). Grid (3,96,4).
// ---------------------------------------------------------------------------
__global__ __launch_bounds__(128) void conv_mfma2_kernel(
    const __hip_bfloat16* __restrict__ xt, const __hip_bfloat16* __restrict__ wt,
    const float* __restrict__ eb, __hip_bfloat16* __restrict__ ft)
{
    const int jb = blockIdx.x;             // 0..2
    const int i  = blockIdx.y;             // 0..95
    const int b  = blockIdx.z;
    const int j0 = jb * 32;
    const int tid  = threadIdx.x;
    const int wave = tid >> 6;             // 0..1 -> cc half
    const int lane = tid & 63;
    const int g = lane >> 4, m = lane & 15;

    __shared__ __align__(16) unsigned int bbuf[2][1728];   // 2 x 6912 B

    const int qq = tid & 3;
    const __hip_bfloat16 *gp0, *gp1, *gp2, *gp3;
    int lb0, lb1, lb2, lb3;
    {
        int r, ku, p;
        r = (tid >> 2);       ku = r / 36; p = r - ku * 36;
        gp0 = xt + ((size_t)((b * 98 + i + ku) * 98 + j0 + p)) * 256 + qq * 8;
        lb0 = (r * 16 + ((qq ^ ((p >> 1) & 3)) << 2)) * 4;
        r = (tid >> 2) + 32;  ku = r / 36; p = r - ku * 36;
        gp1 = xt + ((size_t)((b * 98 + i + ku) * 98 + j0 + p)) * 256 + qq * 8;
        lb1 = (r * 16 + ((qq ^ ((p >> 1) & 3)) << 2)) * 4;
        r = (tid >> 2) + 64;  ku = r / 36; p = r - ku * 36;
        gp2 = xt + ((size_t)((b * 98 + i + ku) * 98 + j0 + p)) * 256 + qq * 8;
        lb2 = (r * 16 + ((qq ^ ((p >> 1) & 3)) << 2)) * 4;
        r = (tid >> 2) + 96;  if (r > 107) r = 107;
        ku = r / 36; p = r - ku * 36;
        gp3 = xt + ((size_t)((b * 98 + i + ku) * 98 + j0 + p)) * 256 + qq * 8;
        lb3 = (r * 16 + ((qq ^ ((p >> 1) & 3)) << 2)) * 4;
    }
    const bool v3 = (tid < 48);

    {
        u32x4 s0 = *(const u32x4*)gp0;
        u32x4 s1 = *(const u32x4*)gp1;
        u32x4 s2 = *(const u32x4*)gp2;
        u32x4 s3 = *(const u32x4*)gp3;
        char* wb = (char*)&bbuf[0][0];
        *(u32x4*)(wb + lb0) = s0;
        *(u32x4*)(wb + lb1) = s1;
        *(u32x4*)(wb + lb2) = s2;
        if (v3) *(u32x4*)(wb + lb3) = s3;
    }
    __syncthreads();

    f32x4 acc00 = (f32x4){0.f,0.f,0.f,0.f}, acc01 = (f32x4){0.f,0.f,0.f,0.f};
    f32x4 acc10 = (f32x4){0.f,0.f,0.f,0.f}, acc11 = (f32x4){0.f,0.f,0.f,0.f};

    const __hip_bfloat16* wA0 = wt + (wave * 2 + 0) * 4096 + g * 128 + m * 8;
    const __hip_bfloat16* wA1 = wt + (wave * 2 + 1) * 4096 + g * 128 + m * 8;

    for (int t = 0; t < 8; ++t) {
        u32x4 s0, s1, s2, s3;
        const bool pf = (t < 7);
        if (pf) {
            const int co = (t + 1) * 32;
            s0 = *(const u32x4*)(gp0 + co);
            s1 = *(const u32x4*)(gp1 + co);
            s2 = *(const u32x4*)(gp2 + co);
            s3 = *(const u32x4*)(gp3 + co);
        }

        const unsigned int* bb = &bbuf[t & 1][0];
        const __hip_bfloat16* wa0 = wA0 + t * 512;
        const __hip_bfloat16* wa1 = wA1 + t * 512;
#pragma unroll
        for (int ku = 0; ku < 3; ++ku) {
#pragma unroll
            for (int kv = 0; kv < 3; ++kv) {
                const int k = ku * 3 + kv;
                bf16x8 a0 = *(const bf16x8*)(wa0 + k * 16384);
                bf16x8 a1 = *(const bf16x8*)(wa1 + k * 16384);
                const int px0 = m + kv, px1 = px0 + 16;
                bf16x8 b0 = *(const bf16x8*)(bb + (ku * 36 + px0) * 16 + ((g ^ ((px0 >> 1) & 3)) << 2));
                bf16x8 b1 = *(const bf16x8*)(bb + (ku * 36 + px1) * 16 + ((g ^ ((px1 >> 1) & 3)) << 2));
                acc00 = __builtin_amdgcn_mfma_f32_16x16x32_bf16(a0, b0, acc00, 0, 0, 0);
                acc01 = __builtin_amdgcn_mfma_f32_16x16x32_bf16(a0, b1, acc01, 0, 0, 0);
                acc10 = __builtin_amdgcn_mfma_f32_16x16x32_bf16(a1, b0, acc10, 0, 0, 0);
                acc11 = __builtin_amdgcn_mfma_f32_16x16x32_bf16(a1, b1, acc11, 0, 0, 0);
            }
        }

        if (pf) {
            char* wb = (char*)&bbuf[(t + 1) & 1][0];
            *(u32x4*)(wb + lb0) = s0;
            *(u32x4*)(wb + lb1) = s1;
            *(u32x4*)(wb + lb2) = s2;
            if (v3) *(u32x4*)(wb + lb3) = s3;
        }
        __syncthreads();
    }

    __hip_bfloat16* out = ft + ((size_t)((b * 100 + i + 2) * 100 + (j0 + 2))) * 64;
#pragma unroll
    for (int mt = 0; mt < 2; ++mt) {
        const int ccb = (wave * 2 + mt) * 16 + g * 4;
        float bias[4];
#pragma unroll
        for (int r = 0; r < 4; ++r) bias[r] = eb[ccb + r];
        f32x4 aN0 = (mt == 0) ? acc00 : acc10;
        f32x4 aN1 = (mt == 0) ? acc01 : acc11;
        u16x4 p0, p1;
#pragma unroll
        for (int r = 0; r < 4; ++r) {
            p0[r] = f2bf(aN0[r] + bias[r]);
            p1[r] = f2bf(aN1[r] + bias[r]);
        }
        *(u16x4*)(out + (0 * 16 + m) * 64 + ccb) = p0;
        *(u16x4*)(out + (1 * 16 + m) * 64 + ccb) = p1;
    }
}

// ---------------------------------------------------------------------------
// CorrProj v2: LDS-staged. Block = 256 thr (4 waves) = 2 rows x 32 px.
// ft window (6 rows x 36 cols x 64ci, XOR-swizzled q^=(col&7)) staged once;
// rwt staged in 10-kc double-buffered super-chunks (2 x 10 KB, linear),
// reg-prefetched during compute (T14). One barrier per super-chunk.
// Wave w: row rw=w>>1, px-half pw=w&1. Grid (3, 48, 4).
// ---------------------------------------------------------------------------
__global__ __launch_bounds__(256) void corrproj_mfma2_kernel(
    const __hip_bfloat16* __restrict__ ft, const __hip_bfloat16* __restrict__ rwt,
    const float* __restrict__ rb, float* __restrict__ y)
{
    const int jb = blockIdx.x;            // 0..2
    const int iy = blockIdx.y;            // 0..47
    const int b  = blockIdx.z;
    const int jc0 = jb * 32, i0 = iy * 2;
    const int tid = threadIdx.x;
    const int wave = tid >> 6, lane = tid & 63;
    const int g = lane >> 4, m = lane & 15;
    const int rw = wave >> 1, pw = wave & 1;

    __shared__ __align__(16) char wnd[6 * 36 * 128];      // 27648 B
    __shared__ __align__(16) char asub[2][5 * 2 * 1024];  // 2 x 10240 B

    // ---- stage ft window: rows i0..i0+5, cols jc0..jc0+35, 64 ci, swizzled
    {
        const __hip_bfloat16* base = ft + ((size_t)((b * 100 + i0) * 100 + jc0)) * 64;
#pragma unroll
        for (int it = 0; it < 7; ++it) {
            int u = it * 256 + tid;
            if (u < 1728) {
                int q = u & 7, rc = u >> 3;
                int col = rc % 36, r = rc / 36;
                u32x4 v = *(const u32x4*)(base + ((size_t)(r * 100 + col)) * 64 + q * 8);
                *(u32x4*)(wnd + (r * 36 + col) * 128 + ((q ^ (col & 7)) << 4)) = v;
            }
        }
    }
    // ---- stage A super-chunk 0 (kc 0..4)
    {
        const u32x4* src = (const u32x4*)rwt;
        u32x4* dst = (u32x4*)&asub[0][0];
        dst[tid] = src[tid];
        dst[tid + 256] = src[tid + 256];
        if (tid < 128) dst[tid + 512] = src[tid + 512];
    }
    __syncthreads();

    // center cache (f32): window[rw+2][pw*16+m+2][h*32+g*8 ..]
    float cen[16];
    {
        const int colc = pw * 16 + m + 2;
        const char* cb = wnd + ((rw + 2) * 36 + colc) * 128;
        bf16x8 c0 = *(const bf16x8*)(cb + ((g ^ (colc & 7)) << 4));
        bf16x8 c1 = *(const bf16x8*)(cb + (((4 + g) ^ (colc & 7)) << 4));
#pragma unroll
        for (int e = 0; e < 8; ++e) {
            cen[e]     = bf2f(c0[e]);
            cen[8 + e] = bf2f(c1[e]);
        }
    }

    f32x4 acc0 = (f32x4){0.f, 0.f, 0.f, 0.f};
    f32x4 acc1 = (f32x4){0.f, 0.f, 0.f, 0.f};

    for (int sc = 0; sc < 10; ++sc) {
        // prefetch next A super-chunk into regs (latency hides under compute)
        u32x4 p0, p1, p2;
        const bool pf = (sc < 9);
        if (pf) {
            const u32x4* src = (const u32x4*)rwt + (sc + 1) * 640;
            p0 = src[tid];
            p1 = src[tid + 256];
            if (tid < 128) p2 = src[tid + 512];
        }

        const char* ab = &asub[sc & 1][0];
#pragma unroll
        for (int kk = 0; kk < 5; ++kk) {
            const int kc = sc * 5 + kk;
            const int uv = kc >> 1, h = kc & 1;
            const int u = uv / 5, v = uv - u * 5;
            bf16x8 a0 = *(const bf16x8*)(ab + (kk * 2 + 0) * 1024 + lane * 16);
            bf16x8 a1 = *(const bf16x8*)(ab + (kk * 2 + 1) * 1024 + lane * 16);
            const int col = pw * 16 + m + v;
            const char* sb = wnd + ((rw + u) * 36 + col) * 128;
            bf16x8 s = *(const bf16x8*)(sb + (((h * 4 + g) ^ (col & 7)) << 4));
            bf16x8 hb;
#pragma unroll
            for (int e = 0; e < 8; ++e)
                hb[e] = (short)f2bf(bf2f(s[e]) * cen[h * 8 + e]);
            acc0 = __builtin_amdgcn_mfma_f32_16x16x32_bf16(a0, hb, acc0, 0, 0, 0);
            acc1 = __builtin_amdgcn_mfma_f32_16x16x32_bf16(a1, hb, acc1, 0, 0, 0);
        }

        if (pf) {
            u32x4* dst = (u32x4*)&asub[(sc + 1) & 1][0];
            dst[tid] = p0;
            dst[tid + 256] = p1;
            if (tid < 128) dst[tid + 512] = p2;
        }
        __syncthreads();
    }

    // epilogue: D[o][px]: o = mt*16 + g*4 + r, px col = m
    const int i = i0 + rw, j0 = jc0 + pw * 16;
#pragma unroll
    for (int r = 0; r < 4; ++r) {
        int o0 = g * 4 + r;
        y[((size_t)(b * OC + o0) * H + i) * W + j0 + m] = acc0[r] + rb[o0];
        int o1 = 16 + g * 4 + r;
        y[((size_t)(b * OC + o1) * H + i) * W + j0 + m] = acc1[r] + rb[o1];
    }
}

extern "C" void kernel_launch(void* const* d_in, const int* in_sizes, int n_in,
                              void* d_out, int out_size, void* d_ws, size_t ws_size,
                              hipStream_t stream) {
    const float* x  = (const float*)d_in[0];
    const float* ew = (const float*)d_in[1];
    const float* eb = (const float*)d_in[2];
    const float* rw = (const float*)d_in[3];
    const float* rb = (const float*)d_in[4];
    float* y = (float*)d_out;

    char* ws = (char*)d_ws;
    __hip_bfloat16* xt  = (__hip_bfloat16*)(ws + XT_OFF);
    __hip_bfloat16* wt  = (__hip_bfloat16*)(ws + WT_OFF);
    __hip_bfloat16* rwt = (__hip_bfloat16*)(ws + RWT_OFF);
    __hip_bfloat16* ft  = (__hip_bfloat16*)(ws + FT_OFF);

    wt_kernel<<<576, 256, 0, stream>>>(ew, wt);
    rwt_kernel<<<200, 256, 0, stream>>>(rw, rwt);
    zero_ft_border_kernel<<<98, 256, 0, stream>>>(ft);
    xt_kernel<<<dim3(98, BATCH), 256, 0, stream>>>(x, xt);
    conv_mfma2_kernel<<<dim3(3, 96, BATCH), 128, 0, stream>>>(xt, wt, eb, ft);
    corrproj_mfma2_kernel<<<dim3(3, 48, BATCH), 256, 0, stream>>>(ft, rwt, rb, y);
}

// Round 6
// 58.955 us; speedup vs baseline: 9.4804x; 1.1389x over previous
//
#include <hip/hip_runtime.h>
#include <hip/hip_bf16.h>

#define BATCH 4
#define CIN 256
#define H 96
#define W 96
#define CC 64
#define OC 32

typedef __attribute__((ext_vector_type(8))) short bf16x8;
typedef __attribute__((ext_vector_type(4))) float f32x4;
typedef __attribute__((ext_vector_type(4))) unsigned short u16x4;
typedef __attribute__((ext_vector_type(4))) unsigned int u32x4;

// workspace layout (bytes)
//   xt : [4][98][98][256] bf16 = 19,668,992
//   wt : [9][4][32][16][8] bf16 =    294,912
//   rwt: [50][2][64][8]   bf16 =    102,400
//   ft : [4][100][100][64] bf16 =  5,120,000
#define XT_OFF  0
#define WT_OFF  19668992
#define RWT_OFF 19963904
#define FT_OFF  20066304

__device__ inline unsigned short f2bf(float v) {
    __hip_bfloat16 t = __float2bfloat16(v);
    return *reinterpret_cast<unsigned short*>(&t);
}
__device__ inline float bf2f(short b) {
    return __uint_as_float(((unsigned int)(unsigned short)b) << 16);
}

// async global->LDS, 16B per lane; LDS dest must be wave-uniform base
__device__ inline void gload_lds16(const __hip_bfloat16* g, void* l) {
    __builtin_amdgcn_global_load_lds(
        (const __attribute__((address_space(1))) unsigned int*)g,
        (__attribute__((address_space(3))) unsigned int*)l, 16, 0, 0);
}

// ---------------------------------------------------------------------------
// Merged prologue: [0,576) wt pack, [576,776) rwt pack, [776,874) ft border 0.
// ---------------------------------------------------------------------------
__global__ __launch_bounds__(256) void prep_kernel(
    const float* __restrict__ ew, const float* __restrict__ rw,
    __hip_bfloat16* __restrict__ wt, __hip_bfloat16* __restrict__ rwt,
    __hip_bfloat16* __restrict__ ft)
{
    const int bid = blockIdx.x;
    const int tid = threadIdx.x;
    if (bid < 576) {
        // wt[k][ccg][cb][m][e] = ew[ccg*16+m][cb*8+e][k]
        int idx = bid * 256 + tid;
        if (idx >= 9 * 4 * 32 * 16 * 8) return;
        int e   = idx & 7;
        int m   = (idx >> 3) & 15;
        int cb  = (idx >> 7) & 31;
        int ccg = (idx >> 12) & 3;
        int k   = idx >> 14;
        int cc = ccg * 16 + m, ci = cb * 8 + e;
        wt[idx] = __float2bfloat16(ew[(cc * CIN + ci) * 9 + k]);
    } else if (bid < 776) {
        // rwt[((kc*2+mt)*64 + lane)*8 + e]; k = kc*32+g*8+e; uv=k>>6; c=k&63
        int idx = (bid - 576) * 256 + tid;
        if (idx >= 50 * 2 * 64 * 8) return;
        int e    = idx & 7;
        int lane = (idx >> 3) & 63;
        int mt   = (idx >> 9) & 1;
        int kc   = idx >> 10;
        int g = lane >> 4, m = lane & 15;
        int o  = mt * 16 + m;
        int k  = kc * 32 + g * 8 + e;
        int uv = k >> 6, c = k & 63;
        rwt[idx] = __float2bfloat16(rw[(o * CC + c) * 25 + uv]);
    } else {
        // zero ft border (interior overwritten by conv)
        int idx = (bid - 776) * 256 + tid;
        if (idx >= 4 * 6272) return;
        int b = idx / 6272, t = idx % 6272;
        int q = t & 7, pid = t >> 3;
        int r, c;
        if (pid < 400) {
            int rr = pid / 100;
            r = (rr < 2) ? rr : rr + 96;
            c = pid % 100;
        } else {
            int p2 = pid - 400;
            r = 2 + (p2 >> 2);
            int c2 = p2 & 3;
            c = (c2 < 2) ? c2 : c2 + 96;
        }
        *(u32x4*)(ft + ((size_t)((b * 100 + r) * 100 + c)) * 64 + q * 8) = (u32x4){0u,0u,0u,0u};
    }
}

// ---------------------------------------------------------------------------
// Prologue B: x -> bf16 channel-last zero-padded layout xt[b][98][98][256]
// ---------------------------------------------------------------------------
__global__ __launch_bounds__(256) void xt_kernel(const float* __restrict__ x,
                                                 __hip_bfloat16* __restrict__ xt)
{
    const int r = blockIdx.x;          // 0..97 (padded row)
    const int b = blockIdx.y;
    const int tid = threadIdx.x;
    __hip_bfloat16* rowp = xt + ((size_t)(b * 98 + r)) * 98 * 256;
    const int gi = r - 1;

    if (gi < 0 || gi >= H) {
        unsigned int* p = (unsigned int*)rowp;
        for (int t = tid; t < 98 * 256 / 2; t += 256) p[t] = 0u;
        return;
    }

    __shared__ __hip_bfloat16 lds[96][258];

    for (int cich = 0; cich < 8; ++cich) {
        int ci = cich * 32 + (tid >> 3);
        const float* src = x + ((size_t)((b * CIN + ci) * H + gi)) * W;
        for (int coli = 0; coli < 3; ++coli) {
            int col = coli * 32 + (tid & 7) * 4;
            float4 v = *(const float4*)(src + col);
            lds[col + 0][ci] = __float2bfloat16(v.x);
            lds[col + 1][ci] = __float2bfloat16(v.y);
            lds[col + 2][ci] = __float2bfloat16(v.z);
            lds[col + 3][ci] = __float2bfloat16(v.w);
        }
    }
    __syncthreads();

    unsigned int* dst = (unsigned int*)rowp;
    for (int it = 0; it < 48; ++it) {
        int col = it * 2 + (tid >> 7);
        int ci2 = tid & 127;
        unsigned int v = *(unsigned int*)&lds[col][ci2 * 2];
        dst[(col + 1) * 128 + ci2] = v;
    }
    if (tid < 128) dst[tid] = 0u;
    else           dst[97 * 128 + (tid - 128)] = 0u;
}

// ---------------------------------------------------------------------------
// Conv v3: block = 128 thr = 2 waves = rows {2iy, 2iy+1}, SAME cc-half (ch
// from grid.z) -> both waves read identical A-frags (L1-shared, L2 traffic /2).
// B staged via global_load_lds: LDS unit U=((r*36+px)*4+s), source quad
// q = s ^ ((px>>1)&3) (pre-swizzled source == swizzled read, rule #21).
// 576 units/chunk = 9 wave-instrs (wave0:5, wave1:4). 2-phase: issue stage
// t+1, compute t (18 A glb + 18 ds_read_b128 + 36 MFMA / wave), barrier.
// Grid (3, 48, 8=b*2+ch).
// ---------------------------------------------------------------------------
__global__ __launch_bounds__(128) void conv_mfma3_kernel(
    const __hip_bfloat16* __restrict__ xt, const __hip_bfloat16* __restrict__ wt,
    const float* __restrict__ eb, __hip_bfloat16* __restrict__ ft)
{
    const int jb = blockIdx.x;            // 0..2
    const int iy = blockIdx.y;            // 0..47
    const int zz = blockIdx.z;            // b*2 + ch
    const int b = zz >> 1, ch = zz & 1;
    const int j0 = jb * 32, i0 = iy * 2;
    const int tid = threadIdx.x;
    const int wid = tid >> 6;             // output-row offset of this wave
    const int lane = tid & 63;
    const int g = lane >> 4, m = lane & 15;

    __shared__ __align__(16) char bbuf[2][9216];   // [buf][576 units x 16B]

    // staging slots: wave0 -> units 0..319 (5 instrs), wave1 -> 320..575 (4)
    const int nslot = 5 - wid;
    const __hip_bfloat16* src0; const __hip_bfloat16* src1;
    const __hip_bfloat16* src2; const __hip_bfloat16* src3;
    const __hip_bfloat16* src4;
    int dst0, dst1, dst2, dst3, dst4;
    {
        const int base = wid * 320;
#define SLOT_INIT(J, SRC, DST)                                                  \
        {                                                                       \
            int U = base + (J) * 64 + lane;                                     \
            if (U > 575) U = 575;                                               \
            int s = U & 3, pxr = U >> 2;                                        \
            int px = pxr % 36, r = pxr / 36;                                    \
            int q = s ^ ((px >> 1) & 3);                                        \
            SRC = xt + ((size_t)((b * 98 + i0 + r) * 98 + j0 + px)) * 256 + q * 8; \
            DST = (base + (J) * 64) * 16;                                       \
        }
        SLOT_INIT(0, src0, dst0)
        SLOT_INIT(1, src1, dst1)
        SLOT_INIT(2, src2, dst2)
        SLOT_INIT(3, src3, dst3)
        SLOT_INIT(4, src4, dst4)
#undef SLOT_INIT
    }

#define STAGE(T, NB)                                                            \
    {                                                                           \
        const int co = (T) * 32;                                                \
        char* lb = &bbuf[(NB)][0];                                              \
        gload_lds16(src0 + co, lb + dst0);                                      \
        gload_lds16(src1 + co, lb + dst1);                                      \
        gload_lds16(src2 + co, lb + dst2);                                      \
        gload_lds16(src3 + co, lb + dst3);                                      \
        if (nslot > 4) gload_lds16(src4 + co, lb + dst4);                       \
    }

    // prologue: stage chunk 0
    STAGE(0, 0)
    __syncthreads();

    f32x4 acc00 = (f32x4){0.f,0.f,0.f,0.f}, acc01 = (f32x4){0.f,0.f,0.f,0.f};
    f32x4 acc10 = (f32x4){0.f,0.f,0.f,0.f}, acc11 = (f32x4){0.f,0.f,0.f,0.f};

    // A: ccg = ch*2 + mt; identical addresses for both waves of the block
    const __hip_bfloat16* wA = wt + (ch * 2) * 4096 + g * 128 + m * 8;

    for (int t = 0; t < 8; ++t) {
        if (t < 7) STAGE(t + 1, (t + 1) & 1)

        const char* bb = &bbuf[t & 1][0];
        const __hip_bfloat16* wa = wA + t * 512;
#pragma unroll
        for (int ku = 0; ku < 3; ++ku) {
#pragma unroll
            for (int kv = 0; kv < 3; ++kv) {
                const int k = ku * 3 + kv;
                bf16x8 a0 = *(const bf16x8*)(wa + k * 16384);
                bf16x8 a1 = *(const bf16x8*)(wa + k * 16384 + 4096);
                const int r = wid + ku;
                const int px0 = m + kv, px1 = px0 + 16;
                bf16x8 b0 = *(const bf16x8*)(bb + ((r * 36 + px0) * 4 + (g ^ ((px0 >> 1) & 3))) * 16);
                bf16x8 b1 = *(const bf16x8*)(bb + ((r * 36 + px1) * 4 + (g ^ ((px1 >> 1) & 3))) * 16);
                acc00 = __builtin_amdgcn_mfma_f32_16x16x32_bf16(a0, b0, acc00, 0, 0, 0);
                acc01 = __builtin_amdgcn_mfma_f32_16x16x32_bf16(a0, b1, acc01, 0, 0, 0);
                acc10 = __builtin_amdgcn_mfma_f32_16x16x32_bf16(a1, b0, acc10, 0, 0, 0);
                acc11 = __builtin_amdgcn_mfma_f32_16x16x32_bf16(a1, b1, acc11, 0, 0, 0);
            }
        }
        __syncthreads();
    }
#undef STAGE

    // epilogue -> ft[b][i0+wid+2][j0+2+px][cc]
    __hip_bfloat16* out = ft + ((size_t)((b * 100 + i0 + wid + 2) * 100 + (j0 + 2))) * 64;
#pragma unroll
    for (int mt = 0; mt < 2; ++mt) {
        const int ccb = (ch * 2 + mt) * 16 + g * 4;
        float bias[4];
#pragma unroll
        for (int r = 0; r < 4; ++r) bias[r] = eb[ccb + r];
        f32x4 aN0 = (mt == 0) ? acc00 : acc10;
        f32x4 aN1 = (mt == 0) ? acc01 : acc11;
        u16x4 p0, p1;
#pragma unroll
        for (int r = 0; r < 4; ++r) {
            p0[r] = f2bf(aN0[r] + bias[r]);
            p1[r] = f2bf(aN1[r] + bias[r]);
        }
        *(u16x4*)(out + (0 * 16 + m) * 64 + ccb) = p0;
        *(u16x4*)(out + (1 * 16 + m) * 64 + ccb) = p1;
    }
}

// ---------------------------------------------------------------------------
// CorrProj (unchanged): LDS-staged K=1600 GEMM, h built in regs.
// ---------------------------------------------------------------------------
__global__ __launch_bounds__(256) void corrproj_mfma2_kernel(
    const __hip_bfloat16* __restrict__ ft, const __hip_bfloat16* __restrict__ rwt,
    const float* __restrict__ rb, float* __restrict__ y)
{
    const int jb = blockIdx.x;            // 0..2
    const int iy = blockIdx.y;            // 0..47
    const int b  = blockIdx.z;
    const int jc0 = jb * 32, i0 = iy * 2;
    const int tid = threadIdx.x;
    const int wave = tid >> 6, lane = tid & 63;
    const int g = lane >> 4, m = lane & 15;
    const int rw = wave >> 1, pw = wave & 1;

    __shared__ __align__(16) char wnd[6 * 36 * 128];      // 27648 B
    __shared__ __align__(16) char asub[2][5 * 2 * 1024];  // 2 x 10240 B

    {
        const __hip_bfloat16* base = ft + ((size_t)((b * 100 + i0) * 100 + jc0)) * 64;
#pragma unroll
        for (int it = 0; it < 7; ++it) {
            int u = it * 256 + tid;
            if (u < 1728) {
                int q = u & 7, rc = u >> 3;
                int col = rc % 36, r = rc / 36;
                u32x4 v = *(const u32x4*)(base + ((size_t)(r * 100 + col)) * 64 + q * 8);
                *(u32x4*)(wnd + (r * 36 + col) * 128 + ((q ^ (col & 7)) << 4)) = v;
            }
        }
    }
    {
        const u32x4* src = (const u32x4*)rwt;
        u32x4* dst = (u32x4*)&asub[0][0];
        dst[tid] = src[tid];
        dst[tid + 256] = src[tid + 256];
        if (tid < 128) dst[tid + 512] = src[tid + 512];
    }
    __syncthreads();

    float cen[16];
    {
        const int colc = pw * 16 + m + 2;
        const char* cb = wnd + ((rw + 2) * 36 + colc) * 128;
        bf16x8 c0 = *(const bf16x8*)(cb + ((g ^ (colc & 7)) << 4));
        bf16x8 c1 = *(const bf16x8*)(cb + (((4 + g) ^ (colc & 7)) << 4));
#pragma unroll
        for (int e = 0; e < 8; ++e) {
            cen[e]     = bf2f(c0[e]);
            cen[8 + e] = bf2f(c1[e]);
        }
    }

    f32x4 acc0 = (f32x4){0.f, 0.f, 0.f, 0.f};
    f32x4 acc1 = (f32x4){0.f, 0.f, 0.f, 0.f};

    for (int sc = 0; sc < 10; ++sc) {
        u32x4 p0, p1, p2;
        const bool pf = (sc < 9);
        if (pf) {
            const u32x4* src = (const u32x4*)rwt + (sc + 1) * 640;
            p0 = src[tid];
            p1 = src[tid + 256];
            if (tid < 128) p2 = src[tid + 512];
        }

        const char* ab = &asub[sc & 1][0];
#pragma unroll
        for (int kk = 0; kk < 5; ++kk) {
            const int kc = sc * 5 + kk;
            const int uv = kc >> 1, h = kc & 1;
            const int u = uv / 5, v = uv - u * 5;
            bf16x8 a0 = *(const bf16x8*)(ab + (kk * 2 + 0) * 1024 + lane * 16);
            bf16x8 a1 = *(const bf16x8*)(ab + (kk * 2 + 1) * 1024 + lane * 16);
            const int col = pw * 16 + m + v;
            const char* sb = wnd + ((rw + u) * 36 + col) * 128;
            bf16x8 s = *(const bf16x8*)(sb + (((h * 4 + g) ^ (col & 7)) << 4));
            bf16x8 hb;
#pragma unroll
            for (int e = 0; e < 8; ++e)
                hb[e] = (short)f2bf(bf2f(s[e]) * cen[h * 8 + e]);
            acc0 = __builtin_amdgcn_mfma_f32_16x16x32_bf16(a0, hb, acc0, 0, 0, 0);
            acc1 = __builtin_amdgcn_mfma_f32_16x16x32_bf16(a1, hb, acc1, 0, 0, 0);
        }

        if (pf) {
            u32x4* dst = (u32x4*)&asub[(sc + 1) & 1][0];
            dst[tid] = p0;
            dst[tid + 256] = p1;
            if (tid < 128) dst[tid + 512] = p2;
        }
        __syncthreads();
    }

    const int i = i0 + rw, j0 = jc0 + pw * 16;
#pragma unroll
    for (int r = 0; r < 4; ++r) {
        int o0 = g * 4 + r;
        y[((size_t)(b * OC + o0) * H + i) * W + j0 + m] = acc0[r] + rb[o0];
        int o1 = 16 + g * 4 + r;
        y[((size_t)(b * OC + o1) * H + i) * W + j0 + m] = acc1[r] + rb[o1];
    }
}

extern "C" void kernel_launch(void* const* d_in, const int* in_sizes, int n_in,
                              void* d_out, int out_size, void* d_ws, size_t ws_size,
                              hipStream_t stream) {
    const float* x  = (const float*)d_in[0];
    const float* ew = (const float*)d_in[1];
    const float* eb = (const float*)d_in[2];
    const float* rw = (const float*)d_in[3];
    const float* rb = (const float*)d_in[4];
    float* y = (float*)d_out;

    char* ws = (char*)d_ws;
    __hip_bfloat16* xt  = (__hip_bfloat16*)(ws + XT_OFF);
    __hip_bfloat16* wt  = (__hip_bfloat16*)(ws + WT_OFF);
    __hip_bfloat16* rwt = (__hip_bfloat16*)(ws + RWT_OFF);
    __hip_bfloat16* ft  = (__hip_bfloat16*)(ws + FT_OFF);

    prep_kernel<<<874, 256, 0, stream>>>(ew, rw, wt, rwt, ft);
    xt_kernel<<<dim3(98, BATCH), 256, 0, stream>>>(x, xt);
    conv_mfma3_kernel<<<dim3(3, 48, 2 * BATCH), 128, 0, stream>>>(xt, wt, eb, ft);
    corrproj_mfma2_kernel<<<dim3(3, 48, BATCH), 256, 0, stream>>>(ft, rwt, rb, y);
}

// Round 7
// 54.178 us; speedup vs baseline: 10.3163x; 1.0882x over previous
//
#include <hip/hip_runtime.h>
#include <hip/hip_bf16.h>

#define BATCH 4
#define CIN 256
#define H 96
#define W 96
#define CC 64
#define OC 32

typedef __attribute__((ext_vector_type(8))) short bf16x8;
typedef __attribute__((ext_vector_type(4))) float f32x4;
typedef __attribute__((ext_vector_type(4))) unsigned short u16x4;
typedef __attribute__((ext_vector_type(4))) unsigned int u32x4;

// workspace layout (bytes)
//   xt : [4][98][98][256] bf16 = 19,668,992
//   wt : [9][4][32][16][8] bf16 =    294,912
//   rwt: [50][2][64][8]   bf16 =    102,400
//   ft : [4][100][100][64] bf16 =  5,120,000
#define XT_OFF  0
#define WT_OFF  19668992
#define RWT_OFF 19963904
#define FT_OFF  20066304

__device__ inline unsigned short f2bf(float v) {
    __hip_bfloat16 t = __float2bfloat16(v);
    return *reinterpret_cast<unsigned short*>(&t);
}
__device__ inline float bf2f(short b) {
    return __uint_as_float(((unsigned int)(unsigned short)b) << 16);
}

// async global->LDS, 16B per lane; LDS dest must be wave-uniform base
__device__ inline void gload_lds16(const __hip_bfloat16* g, void* l) {
    __builtin_amdgcn_global_load_lds(
        (const __attribute__((address_space(1))) unsigned int*)g,
        (__attribute__((address_space(3))) unsigned int*)l, 16, 0, 0);
}

// ---------------------------------------------------------------------------
// Merged prologue+transpose kernel.
// bid <  392 : xt rows — x -> bf16 channel-last zero-padded xt[b][98][98][256]
// bid >= 392 : pb = bid-392: [0,576) wt pack, [576,776) rwt pack,
//              [776,874) ft border zero.
// ---------------------------------------------------------------------------
__global__ __launch_bounds__(256) void prep_xt_kernel(
    const float* __restrict__ x, const float* __restrict__ ew,
    const float* __restrict__ rw, __hip_bfloat16* __restrict__ xt,
    __hip_bfloat16* __restrict__ wt, __hip_bfloat16* __restrict__ rwt,
    __hip_bfloat16* __restrict__ ft)
{
    const int bid = blockIdx.x;
    const int tid = threadIdx.x;

    if (bid >= 392) {
        const int pb = bid - 392;
        if (pb < 576) {
            // wt[k][ccg][cb][m][e] = ew[ccg*16+m][cb*8+e][k]
            int idx = pb * 256 + tid;
            int e   = idx & 7;
            int m   = (idx >> 3) & 15;
            int cb  = (idx >> 7) & 31;
            int ccg = (idx >> 12) & 3;
            int k   = idx >> 14;
            int cc = ccg * 16 + m, ci = cb * 8 + e;
            wt[idx] = __float2bfloat16(ew[(cc * CIN + ci) * 9 + k]);
        } else if (pb < 776) {
            // rwt[((kc*2+mt)*64 + lane)*8 + e]; k = kc*32+g*8+e; uv=k>>6; c=k&63
            int idx = (pb - 576) * 256 + tid;
            if (idx >= 50 * 2 * 64 * 8) return;
            int e    = idx & 7;
            int lane = (idx >> 3) & 63;
            int mt   = (idx >> 9) & 1;
            int kc   = idx >> 10;
            int g = lane >> 4, m = lane & 15;
            int o  = mt * 16 + m;
            int k  = kc * 32 + g * 8 + e;
            int uv = k >> 6, c = k & 63;
            rwt[idx] = __float2bfloat16(rw[(o * CC + c) * 25 + uv]);
        } else {
            // zero ft border (interior overwritten by conv)
            int idx = (pb - 776) * 256 + tid;
            if (idx >= 4 * 6272) return;
            int b = idx / 6272, t = idx % 6272;
            int q = t & 7, pid = t >> 3;
            int r, c;
            if (pid < 400) {
                int rr = pid / 100;
                r = (rr < 2) ? rr : rr + 96;
                c = pid % 100;
            } else {
                int p2 = pid - 400;
                r = 2 + (p2 >> 2);
                int c2 = p2 & 3;
                c = (c2 < 2) ? c2 : c2 + 96;
            }
            *(u32x4*)(ft + ((size_t)((b * 100 + r) * 100 + c)) * 64 + q * 8) = (u32x4){0u,0u,0u,0u};
        }
        return;
    }

    // ---- xt transpose part ----
    const int r = bid % 98;            // padded row
    const int b = bid / 98;
    __hip_bfloat16* rowp = xt + ((size_t)(b * 98 + r)) * 98 * 256;
    const int gi = r - 1;

    if (gi < 0 || gi >= H) {           // border row: zero-fill (16B stores)
        u32x4* p = (u32x4*)rowp;
        const u32x4 z = (u32x4){0u,0u,0u,0u};
        for (int t = tid; t < 98 * 256 * 2 / 16; t += 256) p[t] = z;
        return;
    }

    __shared__ __align__(16) __hip_bfloat16 lds[96][264];   // 528 B rows (16B-mult)

    // phase 1: coalesced fp32 reads, scalar cvt into transposed LDS
    for (int cich = 0; cich < 8; ++cich) {
        int ci = cich * 32 + (tid >> 3);
        const float* src = x + ((size_t)((b * CIN + ci) * H + gi)) * W;
        for (int coli = 0; coli < 3; ++coli) {
            int col = coli * 32 + (tid & 7) * 4;
            float4 v = *(const float4*)(src + col);
            lds[col + 0][ci] = __float2bfloat16(v.x);
            lds[col + 1][ci] = __float2bfloat16(v.y);
            lds[col + 2][ci] = __float2bfloat16(v.z);
            lds[col + 3][ci] = __float2bfloat16(v.w);
        }
    }
    __syncthreads();

    // phase 2: b128 LDS reads, 16B global stores (512 B contiguous per col)
    u32x4* dst16 = (u32x4*)rowp;
#pragma unroll
    for (int it = 0; it < 12; ++it) {
        int u = it * 256 + tid;        // 0..3071
        int col = u >> 5, ci8 = u & 31;
        u32x4 v = *(const u32x4*)&lds[col][ci8 * 8];
        dst16[(col + 1) * 32 + ci8] = v;
    }
    // zero border cols 0 and 97
    if (tid < 32) dst16[tid] = (u32x4){0u,0u,0u,0u};
    else if (tid < 64) dst16[97 * 32 + (tid - 32)] = (u32x4){0u,0u,0u,0u};
}

// ---------------------------------------------------------------------------
// Conv v4: block = 256 thr = 4 waves = output rows {4iq..4iq+3}, SAME cc-half
// (ch from grid.z) -> all 4 waves read identical A-frags (L1-shared; A L2
// traffic halves vs v3). B staged via global_load_lds: unit U=((r*36+px)*4+s),
// r=0..5 (halo 2), source quad q = s ^ ((px>>1)&3) (pre-swizzled source ==
// swizzled read). 864 units/chunk, slots {4,4,3,3}x64/wave, tail clamped into
// pad region (never read). 2-phase double-buffer, one barrier per ci-chunk.
// Grid (3, 24, 8=b*2+ch).
// ---------------------------------------------------------------------------
__global__ __launch_bounds__(256) void conv_mfma4_kernel(
    const __hip_bfloat16* __restrict__ xt, const __hip_bfloat16* __restrict__ wt,
    const float* __restrict__ eb, __hip_bfloat16* __restrict__ ft)
{
    const int jb = blockIdx.x;            // 0..2
    const int iq = blockIdx.y;            // 0..23
    const int zz = blockIdx.z;            // b*2 + ch
    const int b = zz >> 1, ch = zz & 1;
    const int j0 = jb * 32, i0 = iq * 4;
    const int tid = threadIdx.x;
    const int wid = tid >> 6;             // 0..3 = output-row offset
    const int lane = tid & 63;
    const int g = lane >> 4, m = lane & 15;

    __shared__ __align__(16) char bbuf[2][14336];   // 896 units x 16B per buf

    const int start = (wid < 2) ? wid * 256 : 512 + (wid - 2) * 192;
    const int nslot = (wid < 2) ? 4 : 3;

    const __hip_bfloat16* src0; const __hip_bfloat16* src1;
    const __hip_bfloat16* src2; const __hip_bfloat16* src3;
    int dst0, dst1, dst2, dst3;
#define SLOT_INIT(J, SRC, DST)                                                  \
    {                                                                           \
        int U = start + (J) * 64 + lane;                                        \
        if (U > 863) U = 863;                                                   \
        int s = U & 3, pxr = U >> 2;                                            \
        int px = pxr % 36, r = pxr / 36;                                        \
        int q = s ^ ((px >> 1) & 3);                                            \
        SRC = xt + ((size_t)((b * 98 + i0 + r) * 98 + j0 + px)) * 256 + q * 8;  \
        DST = (start + (J) * 64) * 16;                                          \
    }
    SLOT_INIT(0, src0, dst0)
    SLOT_INIT(1, src1, dst1)
    SLOT_INIT(2, src2, dst2)
    SLOT_INIT(3, src3, dst3)
#undef SLOT_INIT

#define STAGE(T, NB)                                                            \
    {                                                                           \
        const int co = (T) * 32;                                                \
        char* lb = &bbuf[(NB)][0];                                              \
        gload_lds16(src0 + co, lb + dst0);                                      \
        gload_lds16(src1 + co, lb + dst1);                                      \
        gload_lds16(src2 + co, lb + dst2);                                      \
        if (nslot > 3) gload_lds16(src3 + co, lb + dst3);                       \
    }

    // prologue: stage chunk 0
    STAGE(0, 0)
    __syncthreads();

    f32x4 acc00 = (f32x4){0.f,0.f,0.f,0.f}, acc01 = (f32x4){0.f,0.f,0.f,0.f};
    f32x4 acc10 = (f32x4){0.f,0.f,0.f,0.f}, acc11 = (f32x4){0.f,0.f,0.f,0.f};

    // A: ccg = ch*2 + mt; identical addresses for all 4 waves of the block
    const __hip_bfloat16* wA = wt + (ch * 2) * 4096 + g * 128 + m * 8;

    for (int t = 0; t < 8; ++t) {
        if (t < 7) STAGE(t + 1, (t + 1) & 1)

        const char* bb = &bbuf[t & 1][0];
        const __hip_bfloat16* wa = wA + t * 512;
#pragma unroll
        for (int ku = 0; ku < 3; ++ku) {
#pragma unroll
            for (int kv = 0; kv < 3; ++kv) {
                const int k = ku * 3 + kv;
                bf16x8 a0 = *(const bf16x8*)(wa + k * 16384);
                bf16x8 a1 = *(const bf16x8*)(wa + k * 16384 + 4096);
                const int r = wid + ku;
                const int px0 = m + kv, px1 = px0 + 16;
                bf16x8 b0 = *(const bf16x8*)(bb + ((r * 36 + px0) * 4 + (g ^ ((px0 >> 1) & 3))) * 16);
                bf16x8 b1 = *(const bf16x8*)(bb + ((r * 36 + px1) * 4 + (g ^ ((px1 >> 1) & 3))) * 16);
                acc00 = __builtin_amdgcn_mfma_f32_16x16x32_bf16(a0, b0, acc00, 0, 0, 0);
                acc01 = __builtin_amdgcn_mfma_f32_16x16x32_bf16(a0, b1, acc01, 0, 0, 0);
                acc10 = __builtin_amdgcn_mfma_f32_16x16x32_bf16(a1, b0, acc10, 0, 0, 0);
                acc11 = __builtin_amdgcn_mfma_f32_16x16x32_bf16(a1, b1, acc11, 0, 0, 0);
            }
        }
        __syncthreads();
    }
#undef STAGE

    // epilogue -> ft[b][i0+wid+2][j0+2+px][cc]
    __hip_bfloat16* out = ft + ((size_t)((b * 100 + i0 + wid + 2) * 100 + (j0 + 2))) * 64;
#pragma unroll
    for (int mt = 0; mt < 2; ++mt) {
        const int ccb = (ch * 2 + mt) * 16 + g * 4;
        float bias[4];
#pragma unroll
        for (int r = 0; r < 4; ++r) bias[r] = eb[ccb + r];
        f32x4 aN0 = (mt == 0) ? acc00 : acc10;
        f32x4 aN1 = (mt == 0) ? acc01 : acc11;
        u16x4 p0, p1;
#pragma unroll
        for (int r = 0; r < 4; ++r) {
            p0[r] = f2bf(aN0[r] + bias[r]);
            p1[r] = f2bf(aN1[r] + bias[r]);
        }
        *(u16x4*)(out + (0 * 16 + m) * 64 + ccb) = p0;
        *(u16x4*)(out + (1 * 16 + m) * 64 + ccb) = p1;
    }
}

// ---------------------------------------------------------------------------
// CorrProj (unchanged): LDS-staged K=1600 GEMM, h built in regs.
// ---------------------------------------------------------------------------
__global__ __launch_bounds__(256) void corrproj_mfma2_kernel(
    const __hip_bfloat16* __restrict__ ft, const __hip_bfloat16* __restrict__ rwt,
    const float* __restrict__ rb, float* __restrict__ y)
{
    const int jb = blockIdx.x;            // 0..2
    const int iy = blockIdx.y;            // 0..47
    const int b  = blockIdx.z;
    const int jc0 = jb * 32, i0 = iy * 2;
    const int tid = threadIdx.x;
    const int wave = tid >> 6, lane = tid & 63;
    const int g = lane >> 4, m = lane & 15;
    const int rw = wave >> 1, pw = wave & 1;

    __shared__ __align__(16) char wnd[6 * 36 * 128];      // 27648 B
    __shared__ __align__(16) char asub[2][5 * 2 * 1024];  // 2 x 10240 B

    {
        const __hip_bfloat16* base = ft + ((size_t)((b * 100 + i0) * 100 + jc0)) * 64;
#pragma unroll
        for (int it = 0; it < 7; ++it) {
            int u = it * 256 + tid;
            if (u < 1728) {
                int q = u & 7, rc = u >> 3;
                int col = rc % 36, r = rc / 36;
                u32x4 v = *(const u32x4*)(base + ((size_t)(r * 100 + col)) * 64 + q * 8);
                *(u32x4*)(wnd + (r * 36 + col) * 128 + ((q ^ (col & 7)) << 4)) = v;
            }
        }
    }
    {
        const u32x4* src = (const u32x4*)rwt;
        u32x4* dst = (u32x4*)&asub[0][0];
        dst[tid] = src[tid];
        dst[tid + 256] = src[tid + 256];
        if (tid < 128) dst[tid + 512] = src[tid + 512];
    }
    __syncthreads();

    float cen[16];
    {
        const int colc = pw * 16 + m + 2;
        const char* cb = wnd + ((rw + 2) * 36 + colc) * 128;
        bf16x8 c0 = *(const bf16x8*)(cb + ((g ^ (colc & 7)) << 4));
        bf16x8 c1 = *(const bf16x8*)(cb + (((4 + g) ^ (colc & 7)) << 4));
#pragma unroll
        for (int e = 0; e < 8; ++e) {
            cen[e]     = bf2f(c0[e]);
            cen[8 + e] = bf2f(c1[e]);
        }
    }

    f32x4 acc0 = (f32x4){0.f, 0.f, 0.f, 0.f};
    f32x4 acc1 = (f32x4){0.f, 0.f, 0.f, 0.f};

    for (int sc = 0; sc < 10; ++sc) {
        u32x4 p0, p1, p2;
        const bool pf = (sc < 9);
        if (pf) {
            const u32x4* src = (const u32x4*)rwt + (sc + 1) * 640;
            p0 = src[tid];
            p1 = src[tid + 256];
            if (tid < 128) p2 = src[tid + 512];
        }

        const char* ab = &asub[sc & 1][0];
#pragma unroll
        for (int kk = 0; kk < 5; ++kk) {
            const int kc = sc * 5 + kk;
            const int uv = kc >> 1, h = kc & 1;
            const int u = uv / 5, v = uv - u * 5;
            bf16x8 a0 = *(const bf16x8*)(ab + (kk * 2 + 0) * 1024 + lane * 16);
            bf16x8 a1 = *(const bf16x8*)(ab + (kk * 2 + 1) * 1024 + lane * 16);
            const int col = pw * 16 + m + v;
            const char* sb = wnd + ((rw + u) * 36 + col) * 128;
            bf16x8 s = *(const bf16x8*)(sb + (((h * 4 + g) ^ (col & 7)) << 4));
            bf16x8 hb;
#pragma unroll
            for (int e = 0; e < 8; ++e)
                hb[e] = (short)f2bf(bf2f(s[e]) * cen[h * 8 + e]);
            acc0 = __builtin_amdgcn_mfma_f32_16x16x32_bf16(a0, hb, acc0, 0, 0, 0);
            acc1 = __builtin_amdgcn_mfma_f32_16x16x32_bf16(a1, hb, acc1, 0, 0, 0);
        }

        if (pf) {
            u32x4* dst = (u32x4*)&asub[(sc + 1) & 1][0];
            dst[tid] = p0;
            dst[tid + 256] = p1;
            if (tid < 128) dst[tid + 512] = p2;
        }
        __syncthreads();
    }

    const int i = i0 + rw, j0 = jc0 + pw * 16;
#pragma unroll
    for (int r = 0; r < 4; ++r) {
        int o0 = g * 4 + r;
        y[((size_t)(b * OC + o0) * H + i) * W + j0 + m] = acc0[r] + rb[o0];
        int o1 = 16 + g * 4 + r;
        y[((size_t)(b * OC + o1) * H + i) * W + j0 + m] = acc1[r] + rb[o1];
    }
}

extern "C" void kernel_launch(void* const* d_in, const int* in_sizes, int n_in,
                              void* d_out, int out_size, void* d_ws, size_t ws_size,
                              hipStream_t stream) {
    const float* x  = (const float*)d_in[0];
    const float* ew = (const float*)d_in[1];
    const float* eb = (const float*)d_in[2];
    const float* rw = (const float*)d_in[3];
    const float* rb = (const float*)d_in[4];
    float* y = (float*)d_out;

    char* ws = (char*)d_ws;
    __hip_bfloat16* xt  = (__hip_bfloat16*)(ws + XT_OFF);
    __hip_bfloat16* wt  = (__hip_bfloat16*)(ws + WT_OFF);
    __hip_bfloat16* rwt = (__hip_bfloat16*)(ws + RWT_OFF);
    __hip_bfloat16* ft  = (__hip_bfloat16*)(ws + FT_OFF);

    prep_xt_kernel<<<1266, 256, 0, stream>>>(x, ew, rw, xt, wt, rwt, ft);
    conv_mfma4_kernel<<<dim3(3, 24, 2 * BATCH), 256, 0, stream>>>(xt, wt, eb, ft);
    corrproj_mfma2_kernel<<<dim3(3, 48, BATCH), 256, 0, stream>>>(ft, rwt, rb, y);
}